// Round 2
// baseline (1472.842 us; speedup 1.0000x reference)
//
#include <hip/hip_runtime.h>
#include <math.h>

#define NN 30000      // nodes
#define NE 60000      // edges
#define NB 500        // graphs
#define YCOLS 1088    // 16*64 (Y) + 64 (Ybias)

__device__ __forceinline__ float sigmoidf_(float x) { return 1.0f / (1.0f + expf(-x)); }

__device__ __forceinline__ int lower_bound_i(const int* __restrict__ a, int n, int v) {
  int lo = 0, hi = n;
  while (lo < hi) { int mid = (lo + hi) >> 1; if (a[mid] < v) lo = mid + 1; else hi = mid; }
  return lo;
}

// ---------------------------------------------------------------------------
// Generic tiled fp32 GEMM: C[M, *] (ldc) tile (m0..m0+63) x (col0 + jt*64 .. +63)
//   A: [M,64] row-major (lda=64, contiguous tiles)
//   B element (k, n) of column-tile jt at: Bbase + jt*cblk + k*kstride + n
// flags: 1=add bias[jt*64+n], 2=relu, 4=add Csrc[row*ldc+col], 8=dual store C2,
//        16="Y mode": tile jt==16 uses `bias` as B (kstride 64) and col 1024
// ---------------------------------------------------------------------------
__global__ __launch_bounds__(256) void gemm64_k(
    const float* __restrict__ A,
    const float* __restrict__ Bbase, long cblk, int kstride,
    float* __restrict__ C, float* __restrict__ C2,
    const float* __restrict__ Csrc, const float* __restrict__ bias,
    int M, int ldc, int col0, int flags)
{
  __shared__ float As[64 * 68];
  __shared__ float Bs[64 * 64];
  const int tid = threadIdx.x;
  const int m0 = blockIdx.x * 64;
  const int jt = blockIdx.y;
  const float* Bp = Bbase + (long)jt * cblk;
  if ((flags & 16) && jt == 16) Bp = bias;  // Ybias tile: B = b_edge viewed [64,64]

  // A tile: contiguous 4096 floats starting at A + m0*64 (guarded)
  {
    const float4* Ag = (const float4*)(A + (size_t)m0 * 64);
    const int lim = (M - m0) * 16;  // valid float4s in tile
#pragma unroll
    for (int i = 0; i < 4; i++) {
      int f4 = tid + i * 256;
      float4 v = make_float4(0.f, 0.f, 0.f, 0.f);
      if (f4 < lim) v = Ag[f4];
      int f = f4 << 2;
      int row = f >> 6, k = f & 63;
      *(float4*)&As[row * 68 + k] = v;
    }
#pragma unroll
    for (int i = 0; i < 4; i++) {
      int f4 = tid + i * 256;
      int f = f4 << 2;
      int k = f >> 6, n = f & 63;
      float4 v = *(const float4*)(Bp + (long)k * kstride + n);
      *(float4*)&Bs[k * 64 + n] = v;
    }
  }
  __syncthreads();

  const int tx = tid & 15, ty = tid >> 4;
  const float* As0 = As + (ty * 4 + 0) * 68;
  const float* As1 = As + (ty * 4 + 1) * 68;
  const float* As2 = As + (ty * 4 + 2) * 68;
  const float* As3 = As + (ty * 4 + 3) * 68;
  float acc[4][4] = {};
#pragma unroll
  for (int k = 0; k < 64; k++) {
    float4 b = *(const float4*)(Bs + k * 64 + tx * 4);
    float a0 = As0[k], a1 = As1[k], a2 = As2[k], a3 = As3[k];
    acc[0][0] = fmaf(a0, b.x, acc[0][0]); acc[0][1] = fmaf(a0, b.y, acc[0][1]);
    acc[0][2] = fmaf(a0, b.z, acc[0][2]); acc[0][3] = fmaf(a0, b.w, acc[0][3]);
    acc[1][0] = fmaf(a1, b.x, acc[1][0]); acc[1][1] = fmaf(a1, b.y, acc[1][1]);
    acc[1][2] = fmaf(a1, b.z, acc[1][2]); acc[1][3] = fmaf(a1, b.w, acc[1][3]);
    acc[2][0] = fmaf(a2, b.x, acc[2][0]); acc[2][1] = fmaf(a2, b.y, acc[2][1]);
    acc[2][2] = fmaf(a2, b.z, acc[2][2]); acc[2][3] = fmaf(a2, b.w, acc[2][3]);
    acc[3][0] = fmaf(a3, b.x, acc[3][0]); acc[3][1] = fmaf(a3, b.y, acc[3][1]);
    acc[3][2] = fmaf(a3, b.z, acc[3][2]); acc[3][3] = fmaf(a3, b.w, acc[3][3]);
  }

  const int coln = tx * 4;
  int colt = jt * 64;
  if ((flags & 16) && jt == 16) colt = 1024;
  const int col = col0 + colt + coln;
#pragma unroll
  for (int i = 0; i < 4; i++) {
    int row = m0 + ty * 4 + i;
    if (row < M) {
      float v0 = acc[i][0], v1 = acc[i][1], v2 = acc[i][2], v3 = acc[i][3];
      size_t off = (size_t)row * ldc + col;
      if (flags & 4) {
        float4 s = *(const float4*)(Csrc + off);
        v0 += s.x; v1 += s.y; v2 += s.z; v3 += s.w;
      }
      if (flags & 1) {
        int bi = jt * 64 + coln;
        v0 += bias[bi + 0]; v1 += bias[bi + 1]; v2 += bias[bi + 2]; v3 += bias[bi + 3];
      }
      if (flags & 2) {
        v0 = fmaxf(v0, 0.f); v1 = fmaxf(v1, 0.f); v2 = fmaxf(v2, 0.f); v3 = fmaxf(v3, 0.f);
      }
      float4 v = make_float4(v0, v1, v2, v3);
      *(float4*)&C[off] = v;
      if (flags & 8) *(float4*)&C2[off] = v;
    }
  }
}

// Build WT[64][384]: cols 0..191 = gru_W_ih^T, 192..383 = gru_W_hh^T
__global__ __launch_bounds__(256) void prep_wt_k(
    const float* __restrict__ Wih, const float* __restrict__ Whh, float* __restrict__ WT)
{
  int idx = blockIdx.x * 256 + threadIdx.x;
  if (idx >= 64 * 384) return;
  int k = idx / 384, j = idx % 384;
  WT[idx] = (j < 192) ? Wih[j * 64 + k] : Whh[(j - 192) * 64 + k];
}

// One wave per edge: msg[o] = Ybias[src][o] + sum_c ea[e,c]*Y[src, c*64+o]; atomic into aggr[dst]
__global__ __launch_bounds__(256) void edge_msg_k(
    const int* __restrict__ ei, const float* __restrict__ ea,
    const float* __restrict__ Y, float* __restrict__ aggr)
{
  int gw = (blockIdx.x * blockDim.x + threadIdx.x) >> 6;
  if (gw >= NE) return;
  int lane = threadIdx.x & 63;
  int src = ei[gw];
  int dst = ei[NE + gw];
  const float* y = Y + (size_t)src * YCOLS;
  const float* eav = ea + (size_t)gw * 16;
  float4 e0 = *(const float4*)(eav + 0);
  float4 e1 = *(const float4*)(eav + 4);
  float4 e2 = *(const float4*)(eav + 8);
  float4 e3 = *(const float4*)(eav + 12);
  float msg = y[1024 + lane];
  msg = fmaf(e0.x, y[0 * 64 + lane], msg);  msg = fmaf(e0.y, y[1 * 64 + lane], msg);
  msg = fmaf(e0.z, y[2 * 64 + lane], msg);  msg = fmaf(e0.w, y[3 * 64 + lane], msg);
  msg = fmaf(e1.x, y[4 * 64 + lane], msg);  msg = fmaf(e1.y, y[5 * 64 + lane], msg);
  msg = fmaf(e1.z, y[6 * 64 + lane], msg);  msg = fmaf(e1.w, y[7 * 64 + lane], msg);
  msg = fmaf(e2.x, y[8 * 64 + lane], msg);  msg = fmaf(e2.y, y[9 * 64 + lane], msg);
  msg = fmaf(e2.z, y[10 * 64 + lane], msg); msg = fmaf(e2.w, y[11 * 64 + lane], msg);
  msg = fmaf(e3.x, y[12 * 64 + lane], msg); msg = fmaf(e3.y, y[13 * 64 + lane], msg);
  msg = fmaf(e3.z, y[14 * 64 + lane], msg); msg = fmaf(e3.w, y[15 * 64 + lane], msg);
  atomicAdd(&aggr[(size_t)dst * 64 + lane], msg);
}

// GRU elementwise: h = (1-z)*n + z*h
__global__ __launch_bounds__(256) void gru_elem_k(
    const float* __restrict__ gi, const float* __restrict__ gh, float* __restrict__ h)
{
  int t = blockIdx.x * 256 + threadIdx.x;
  if (t >= NN * 64) return;
  int n = t >> 6, c = t & 63;
  const float* gin = gi + (size_t)n * 192;
  const float* ghn = gh + (size_t)n * 192;
  float r = sigmoidf_(gin[c] + ghn[c]);
  float z = sigmoidf_(gin[64 + c] + ghn[64 + c]);
  float ng = tanhf(gin[128 + c] + r * ghn[128 + c]);
  float hv = h[t];
  h[t] = (1.f - z) * ng + z * hv;
}

// xcat = [h0, h]; p_borylation = h @ W_cls + b_cls  (one wave per node)
__global__ __launch_bounds__(256) void xcat_cls_k(
    const float* __restrict__ h0, const float* __restrict__ h,
    const float* __restrict__ Wcls, const float* __restrict__ bcls,
    float* __restrict__ xcat, float* __restrict__ out)
{
  int gw = (blockIdx.x * blockDim.x + threadIdx.x) >> 6;
  if (gw >= NN) return;
  int lane = threadIdx.x & 63;
  float hv = h[(size_t)gw * 64 + lane];
  xcat[(size_t)gw * 128 + lane] = h0[(size_t)gw * 64 + lane];
  xcat[(size_t)gw * 128 + 64 + lane] = hv;
  float p = hv * Wcls[lane];
#pragma unroll
  for (int off = 32; off > 0; off >>= 1) p += __shfl_xor(p, off);
  if (lane == 0) out[gw] = p + bcls[0];
}

// LSTM step on [NB] graphs: 16 graphs per block
__global__ __launch_bounds__(256) void lstm_step_k(
    const float* __restrict__ q_star, float* __restrict__ hs, float* __restrict__ cs,
    const float* __restrict__ Wih, const float* __restrict__ Whh,
    const float* __restrict__ bih, const float* __restrict__ bhh)
{
  __shared__ float qs[16 * 256];
  __shared__ float hsl[16 * 128];
  int g0 = blockIdx.x * 16;
  int tid = threadIdx.x;
  int nvalid = NB - g0; if (nvalid > 16) nvalid = 16;
#pragma unroll
  for (int i = 0; i < 16; i++) {
    int f = tid + i * 256;
    qs[f] = (f < nvalid * 256) ? q_star[(size_t)g0 * 256 + f] : 0.f;
  }
#pragma unroll
  for (int i = 0; i < 8; i++) {
    int f = tid + i * 256;
    hsl[f] = (f < nvalid * 128) ? hs[(size_t)g0 * 128 + f] : 0.f;
  }
  __syncthreads();
  int d = tid & 127, half = tid >> 7;
  float ai[8] = {}, af[8] = {}, ag[8] = {}, ao[8] = {};
  const float* wi = Wih + (size_t)d * 256;
  const float* wf = Wih + (size_t)(128 + d) * 256;
  const float* wg = Wih + (size_t)(256 + d) * 256;
  const float* wo = Wih + (size_t)(384 + d) * 256;
  const float* qb = qs + half * 8 * 256;
  for (int j = 0; j < 256; j++) {
    float vi = wi[j], vf = wf[j], vg = wg[j], vo = wo[j];
#pragma unroll
    for (int g = 0; g < 8; g++) {
      float qv = qb[g * 256 + j];
      ai[g] = fmaf(qv, vi, ai[g]); af[g] = fmaf(qv, vf, af[g]);
      ag[g] = fmaf(qv, vg, ag[g]); ao[g] = fmaf(qv, vo, ao[g]);
    }
  }
  const float* ui = Whh + (size_t)d * 128;
  const float* uf = Whh + (size_t)(128 + d) * 128;
  const float* ug = Whh + (size_t)(256 + d) * 128;
  const float* uo = Whh + (size_t)(384 + d) * 128;
  const float* hb = hsl + half * 8 * 128;
  for (int j = 0; j < 128; j++) {
    float vi = ui[j], vf = uf[j], vg = ug[j], vo = uo[j];
#pragma unroll
    for (int g = 0; g < 8; g++) {
      float hv = hb[g * 128 + j];
      ai[g] = fmaf(hv, vi, ai[g]); af[g] = fmaf(hv, vf, af[g]);
      ag[g] = fmaf(hv, vg, ag[g]); ao[g] = fmaf(hv, vo, ao[g]);
    }
  }
  float b_i = bih[d] + bhh[d];
  float b_f = bih[128 + d] + bhh[128 + d];
  float b_g = bih[256 + d] + bhh[256 + d];
  float b_o = bih[384 + d] + bhh[384 + d];
#pragma unroll
  for (int g = 0; g < 8; g++) {
    int gb = g0 + half * 8 + g;
    if (gb < NB) {
      float iv = sigmoidf_(ai[g] + b_i);
      float fv = sigmoidf_(af[g] + b_f);
      float gv = tanhf(ag[g] + b_g);
      float ov = sigmoidf_(ao[g] + b_o);
      float c = fv * cs[(size_t)gb * 128 + d] + iv * gv;
      cs[(size_t)gb * 128 + d] = c;
      hs[(size_t)gb * 128 + d] = ov * tanhf(c);
    }
  }
}

// Segment-softmax attention + readout: one block per graph
__global__ __launch_bounds__(256) void attn_k(
    const float* __restrict__ xcat, const int* __restrict__ batch,
    const float* __restrict__ hs, float* __restrict__ e_ws, float* __restrict__ q_star)
{
  __shared__ float q[128];
  __shared__ float red[4];
  __shared__ float rvw[4 * 128];
  __shared__ float dw[4];
  __shared__ int se[2];
  int b = blockIdx.x;
  int tid = threadIdx.x;
  if (tid < 128) q[tid] = hs[(size_t)b * 128 + tid];
  if (tid == 254) se[0] = lower_bound_i(batch, NN, b);
  if (tid == 255) se[1] = lower_bound_i(batch, NN, b + 1);
  __syncthreads();
  int start = se[0], end = se[1];
  int lane = tid & 63, w = tid >> 6;
  float wmax = -INFINITY;
  for (int n = start + w; n < end; n += 4) {
    const float* xr = xcat + (size_t)n * 128;
    float p = xr[lane] * q[lane] + xr[64 + lane] * q[64 + lane];
#pragma unroll
    for (int off = 32; off > 0; off >>= 1) p += __shfl_xor(p, off);
    if (lane == 0) e_ws[n] = p;
    wmax = fmaxf(wmax, p);
  }
  if (lane == 0) red[w] = wmax;
  __syncthreads();
  float bmax = fmaxf(fmaxf(red[0], red[1]), fmaxf(red[2], red[3]));
  float a0 = 0.f, a1 = 0.f, ds = 0.f;
  for (int n = start + w; n < end; n += 4) {
    float ex = expf(e_ws[n] - bmax);
    const float* xr = xcat + (size_t)n * 128;
    a0 = fmaf(ex, xr[lane], a0);
    a1 = fmaf(ex, xr[64 + lane], a1);
    ds += ex;
  }
  rvw[w * 128 + lane] = a0;
  rvw[w * 128 + 64 + lane] = a1;
  if (lane == 0) dw[w] = ds;
  __syncthreads();
  if (tid < 128) {
    float r = rvw[tid] + rvw[128 + tid] + rvw[256 + tid] + rvw[384 + tid];
    float dsum = dw[0] + dw[1] + dw[2] + dw[3];
    q_star[(size_t)b * 256 + tid] = q[tid];
    q_star[(size_t)b * 256 + 128 + tid] = (end > start) ? (r / dsum) : 0.f;
  }
}

// Final head: 8 graphs per block: gf(1024,PReLU) -> y1(128,ReLU) -> y(1)
__global__ __launch_bounds__(256) void head_k(
    const float* __restrict__ q_star,
    const float* __restrict__ Wsp, const float* __restrict__ bsp, const float* __restrict__ pa,
    const float* __restrict__ Wy1, const float* __restrict__ by1,
    const float* __restrict__ Wy2, const float* __restrict__ by2,
    float* __restrict__ out)
{
  __shared__ float qs[8 * 256];
  __shared__ float gf[8 * 1024];
  __shared__ float y1[8 * 128];
  int g0 = blockIdx.x * 8;
  int tid = threadIdx.x;
  int lim = (NB - g0) * 256;
#pragma unroll
  for (int i = 0; i < 8; i++) {
    int f = tid + i * 256;
    qs[f] = (f < lim) ? q_star[(size_t)g0 * 256 + f] : 0.f;
  }
  __syncthreads();
  float alpha = pa[0];
#pragma unroll
  for (int kk = 0; kk < 4; kk++) {
    int r = tid + kk * 256;
    float acc[8] = {};
    for (int j = 0; j < 256; j++) {
      float wv = Wsp[(size_t)j * 1024 + r];
#pragma unroll
      for (int g = 0; g < 8; g++) acc[g] = fmaf(qs[g * 256 + j], wv, acc[g]);
    }
    float bb = bsp[r];
#pragma unroll
    for (int g = 0; g < 8; g++) {
      float v = acc[g] + bb;
      gf[g * 1024 + r] = (v >= 0.f) ? v : alpha * v;
    }
  }
  __syncthreads();
  {
    int d = tid & 127, hf = tid >> 7;
    float acc[4] = {};
    for (int r = 0; r < 1024; r++) {
      float wv = Wy1[(size_t)r * 128 + d];
#pragma unroll
      for (int g = 0; g < 4; g++) acc[g] = fmaf(gf[(hf * 4 + g) * 1024 + r], wv, acc[g]);
    }
    float bb = by1[d];
#pragma unroll
    for (int g = 0; g < 4; g++) y1[(hf * 4 + g) * 128 + d] = fmaxf(acc[g] + bb, 0.f);
  }
  __syncthreads();
  {
    int lane = tid & 63, w = tid >> 6;
#pragma unroll
    for (int g = w; g < 8; g += 4) {
      float p = y1[g * 128 + lane] * Wy2[lane] + y1[g * 128 + 64 + lane] * Wy2[64 + lane];
#pragma unroll
      for (int off = 32; off > 0; off >>= 1) p += __shfl_xor(p, off);
      if (lane == 0 && (g0 + g) < NB) out[g0 + g] = p + by2[0];
    }
  }
}

extern "C" void kernel_launch(void* const* d_in, const int* in_sizes, int n_in,
                              void* d_out, int out_size, void* d_ws, size_t ws_size,
                              hipStream_t stream) {
  const float* x      = (const float*)d_in[0];
  const int*   ei     = (const int*)d_in[1];
  const float* ea     = (const float*)d_in[2];
  const int*   batch  = (const int*)d_in[3];
  const float* W_proj = (const float*)d_in[4];
  const float* b_proj = (const float*)d_in[5];
  const float* W_edge = (const float*)d_in[6];
  const float* b_edge = (const float*)d_in[7];
  const float* root   = (const float*)d_in[8];
  const float* conv_b = (const float*)d_in[9];
  const float* gWih   = (const float*)d_in[10];
  const float* gWhh   = (const float*)d_in[11];
  const float* gbih   = (const float*)d_in[12];
  const float* gbhh   = (const float*)d_in[13];
  const float* Wcls   = (const float*)d_in[14];
  const float* bcls   = (const float*)d_in[15];
  const float* lWih   = (const float*)d_in[16];
  const float* lWhh   = (const float*)d_in[17];
  const float* lbih   = (const float*)d_in[18];
  const float* lbhh   = (const float*)d_in[19];
  const float* Wsp    = (const float*)d_in[20];
  const float* bsp    = (const float*)d_in[21];
  const float* pa     = (const float*)d_in[22];
  const float* Wy1    = (const float*)d_in[23];
  const float* by1    = (const float*)d_in[24];
  const float* Wy2    = (const float*)d_in[25];
  const float* by2    = (const float*)d_in[26];
  float* out = (float*)d_out;

  float* ws = (float*)d_ws;
  size_t o = 0;
  float* h0     = ws + o; o += (size_t)NN * 64;
  float* h      = ws + o; o += (size_t)NN * 64;
  float* Y      = ws + o; o += (size_t)NN * YCOLS;
  float* aggr   = ws + o; o += (size_t)NN * 64;
  float* mbuf   = ws + o; o += (size_t)NN * 64;
  float* gi     = ws + o; o += (size_t)NN * 192;
  float* gh     = ws + o; o += (size_t)NN * 192;
  float* xcat   = ws + o; o += (size_t)NN * 128;
  float* e_ws   = ws + o; o += (size_t)NN;
  float* WT     = ws + o; o += 64 * 384;
  float* q_star = ws + o; o += (size_t)NB * 256;
  float* hs     = ws + o; o += (size_t)NB * 128;
  float* cs     = ws + o; o += (size_t)NB * 128;

  const int MT = (NN + 63) / 64;  // 469 row tiles

  prep_wt_k<<<96, 256, 0, stream>>>(gWih, gWhh, WT);
  // h0 = relu(x @ W_proj + b_proj); h = h0
  gemm64_k<<<dim3(MT, 1), 256, 0, stream>>>(x, W_proj, 0, 64, h0, h, nullptr, b_proj,
                                            NN, 64, 0, 1 | 2 | 8);
  for (int step = 0; step < 3; step++) {
    hipMemsetAsync(aggr, 0, (size_t)NN * 64 * sizeof(float), stream);
    // Y[:, c*64+o] = h @ W_edge[c] (tiles 0..15); Y[:,1024+o] = h @ b_edge (tile 16)
    gemm64_k<<<dim3(MT, 17), 256, 0, stream>>>(h, W_edge, 4096, 64, Y, nullptr, nullptr, b_edge,
                                               NN, YCOLS, 0, 16);
    edge_msg_k<<<(NE * 64) / 256, 256, 0, stream>>>(ei, ea, Y, aggr);
    // m = relu(aggr + h @ root + conv_bias)
    gemm64_k<<<dim3(MT, 1), 256, 0, stream>>>(h, root, 0, 64, mbuf, nullptr, aggr, conv_b,
                                              NN, 64, 0, 1 | 2 | 4);
    // gi = m @ W_ih^T + b_ih ; gh = h @ W_hh^T + b_hh
    gemm64_k<<<dim3(MT, 3), 256, 0, stream>>>(mbuf, WT, 64, 384, gi, nullptr, nullptr, gbih,
                                              NN, 192, 0, 1);
    gemm64_k<<<dim3(MT, 3), 256, 0, stream>>>(h, WT + 192, 64, 384, gh, nullptr, nullptr, gbhh,
                                              NN, 192, 0, 1);
    gru_elem_k<<<(NN * 64) / 256, 256, 0, stream>>>(gi, gh, h);
  }
  xcat_cls_k<<<(NN * 64) / 256, 256, 0, stream>>>(h0, h, Wcls, bcls, xcat, out);
  hipMemsetAsync(q_star, 0, (size_t)NB * (256 + 128 + 128) * sizeof(float), stream);
  for (int t = 0; t < 3; t++) {
    lstm_step_k<<<(NB + 15) / 16, 256, 0, stream>>>(q_star, hs, cs, lWih, lWhh, lbih, lbhh);
    attn_k<<<NB, 256, 0, stream>>>(xcat, batch, hs, e_ws, q_star);
  }
  head_k<<<(NB + 7) / 8, 256, 0, stream>>>(q_star, Wsp, bsp, pa, Wy1, by1, Wy2, by2, out + NN);
}

// Round 3
// 1282.437 us; speedup vs baseline: 1.1485x; 1.1485x over previous
//
#include <hip/hip_runtime.h>
#include <math.h>

#define NN 30000      // nodes
#define NE 60000      // edges
#define NB 500        // graphs
#define YCOLS 1088    // 16*64 (Y) + 64 (Ybias)

__device__ __forceinline__ float sigmoidf_(float x) { return 1.0f / (1.0f + expf(-x)); }

__device__ __forceinline__ int lower_bound_i(const int* __restrict__ a, int n, int v) {
  int lo = 0, hi = n;
  while (lo < hi) { int mid = (lo + hi) >> 1; if (a[mid] < v) lo = mid + 1; else hi = mid; }
  return lo;
}

// ---------------------------------------------------------------------------
// Tiled fp32 GEMM, K=64 single-shot (node-side layers). See round-0 notes.
// flags: 1=add bias[jt*64+n], 2=relu, 4=add Csrc, 8=dual store C2,
//        16="Y mode": tile jt==16 uses `bias` as B (kstride 64) and col 1024
// ---------------------------------------------------------------------------
__global__ __launch_bounds__(256) void gemm64_k(
    const float* __restrict__ A,
    const float* __restrict__ Bbase, long cblk, int kstride,
    float* __restrict__ C, float* __restrict__ C2,
    const float* __restrict__ Csrc, const float* __restrict__ bias,
    int M, int ldc, int col0, int flags)
{
  __shared__ float As[64 * 68];
  __shared__ float Bs[64 * 64];
  const int tid = threadIdx.x;
  const int m0 = blockIdx.x * 64;
  const int jt = blockIdx.y;
  const float* Bp = Bbase + (long)jt * cblk;
  if ((flags & 16) && jt == 16) Bp = bias;  // Ybias tile: B = b_edge viewed [64,64]

  {
    const float4* Ag = (const float4*)(A + (size_t)m0 * 64);
    const int lim = (M - m0) * 16;
#pragma unroll
    for (int i = 0; i < 4; i++) {
      int f4 = tid + i * 256;
      float4 v = make_float4(0.f, 0.f, 0.f, 0.f);
      if (f4 < lim) v = Ag[f4];
      int f = f4 << 2;
      int row = f >> 6, k = f & 63;
      *(float4*)&As[row * 68 + k] = v;
    }
#pragma unroll
    for (int i = 0; i < 4; i++) {
      int f4 = tid + i * 256;
      int f = f4 << 2;
      int k = f >> 6, n = f & 63;
      float4 v = *(const float4*)(Bp + (long)k * kstride + n);
      *(float4*)&Bs[k * 64 + n] = v;
    }
  }
  __syncthreads();

  const int tx = tid & 15, ty = tid >> 4;
  const float* As0 = As + (ty * 4 + 0) * 68;
  const float* As1 = As + (ty * 4 + 1) * 68;
  const float* As2 = As + (ty * 4 + 2) * 68;
  const float* As3 = As + (ty * 4 + 3) * 68;
  float acc[4][4] = {};
#pragma unroll
  for (int k = 0; k < 64; k++) {
    float4 b = *(const float4*)(Bs + k * 64 + tx * 4);
    float a0 = As0[k], a1 = As1[k], a2 = As2[k], a3 = As3[k];
    acc[0][0] = fmaf(a0, b.x, acc[0][0]); acc[0][1] = fmaf(a0, b.y, acc[0][1]);
    acc[0][2] = fmaf(a0, b.z, acc[0][2]); acc[0][3] = fmaf(a0, b.w, acc[0][3]);
    acc[1][0] = fmaf(a1, b.x, acc[1][0]); acc[1][1] = fmaf(a1, b.y, acc[1][1]);
    acc[1][2] = fmaf(a1, b.z, acc[1][2]); acc[1][3] = fmaf(a1, b.w, acc[1][3]);
    acc[2][0] = fmaf(a2, b.x, acc[2][0]); acc[2][1] = fmaf(a2, b.y, acc[2][1]);
    acc[2][2] = fmaf(a2, b.z, acc[2][2]); acc[2][3] = fmaf(a2, b.w, acc[2][3]);
    acc[3][0] = fmaf(a3, b.x, acc[3][0]); acc[3][1] = fmaf(a3, b.y, acc[3][1]);
    acc[3][2] = fmaf(a3, b.z, acc[3][2]); acc[3][3] = fmaf(a3, b.w, acc[3][3]);
  }

  const int coln = tx * 4;
  int colt = jt * 64;
  if ((flags & 16) && jt == 16) colt = 1024;
  const int col = col0 + colt + coln;
#pragma unroll
  for (int i = 0; i < 4; i++) {
    int row = m0 + ty * 4 + i;
    if (row < M) {
      float v0 = acc[i][0], v1 = acc[i][1], v2 = acc[i][2], v3 = acc[i][3];
      size_t off = (size_t)row * ldc + col;
      if (flags & 4) {
        float4 s = *(const float4*)(Csrc + off);
        v0 += s.x; v1 += s.y; v2 += s.z; v3 += s.w;
      }
      if (flags & 1) {
        int bi = jt * 64 + coln;
        v0 += bias[bi + 0]; v1 += bias[bi + 1]; v2 += bias[bi + 2]; v3 += bias[bi + 3];
      }
      if (flags & 2) {
        v0 = fmaxf(v0, 0.f); v1 = fmaxf(v1, 0.f); v2 = fmaxf(v2, 0.f); v3 = fmaxf(v3, 0.f);
      }
      float4 v = make_float4(v0, v1, v2, v3);
      *(float4*)&C[off] = v;
      if (flags & 8) *(float4*)&C2[off] = v;
    }
  }
}

// ---------------------------------------------------------------------------
// General K-loop fp32 GEMM: C[m0..m0+63, n0..n0+63] += A[M,lda] @ B[K,ldb]
// K, N(=grid.y*64) multiples of 64; M arbitrary (row-guarded).
// flags: 1=bias[n], 2=relu, 4=add Csrc, 32=PReLU(alpha_p[0])
// ---------------------------------------------------------------------------
__global__ __launch_bounds__(256) void gemmK_k(
    const float* __restrict__ A, int lda,
    const float* __restrict__ B, int ldb,
    float* __restrict__ C, int ldc,
    const float* __restrict__ Csrc,
    const float* __restrict__ bias, const float* __restrict__ alpha_p,
    int M, int K, int flags)
{
  __shared__ float As[64 * 68];
  __shared__ float Bs[64 * 64];
  const int tid = threadIdx.x;
  const int m0 = blockIdx.x * 64;
  const int n0 = blockIdx.y * 64;
  const int tx = tid & 15, ty = tid >> 4;
  float acc[4][4] = {};

  for (int kc = 0; kc < K; kc += 64) {
#pragma unroll
    for (int i = 0; i < 4; i++) {
      int f4 = tid + i * 256;          // 0..1023 float4 slots
      int row = f4 >> 4;
      int kk = (f4 & 15) << 2;
      float4 v = make_float4(0.f, 0.f, 0.f, 0.f);
      if (m0 + row < M) v = *(const float4*)(A + (size_t)(m0 + row) * lda + kc + kk);
      *(float4*)&As[row * 68 + kk] = v;
    }
#pragma unroll
    for (int i = 0; i < 4; i++) {
      int f4 = tid + i * 256;
      int kk = f4 >> 4;
      int nn = (f4 & 15) << 2;
      float4 v = *(const float4*)(B + (size_t)(kc + kk) * ldb + n0 + nn);
      *(float4*)&Bs[kk * 64 + nn] = v;
    }
    __syncthreads();
    const float* As0 = As + (ty * 4 + 0) * 68;
    const float* As1 = As + (ty * 4 + 1) * 68;
    const float* As2 = As + (ty * 4 + 2) * 68;
    const float* As3 = As + (ty * 4 + 3) * 68;
#pragma unroll
    for (int k = 0; k < 64; k++) {
      float4 b = *(const float4*)(Bs + k * 64 + tx * 4);
      float a0 = As0[k], a1 = As1[k], a2 = As2[k], a3 = As3[k];
      acc[0][0] = fmaf(a0, b.x, acc[0][0]); acc[0][1] = fmaf(a0, b.y, acc[0][1]);
      acc[0][2] = fmaf(a0, b.z, acc[0][2]); acc[0][3] = fmaf(a0, b.w, acc[0][3]);
      acc[1][0] = fmaf(a1, b.x, acc[1][0]); acc[1][1] = fmaf(a1, b.y, acc[1][1]);
      acc[1][2] = fmaf(a1, b.z, acc[1][2]); acc[1][3] = fmaf(a1, b.w, acc[1][3]);
      acc[2][0] = fmaf(a2, b.x, acc[2][0]); acc[2][1] = fmaf(a2, b.y, acc[2][1]);
      acc[2][2] = fmaf(a2, b.z, acc[2][2]); acc[2][3] = fmaf(a2, b.w, acc[2][3]);
      acc[3][0] = fmaf(a3, b.x, acc[3][0]); acc[3][1] = fmaf(a3, b.y, acc[3][1]);
      acc[3][2] = fmaf(a3, b.z, acc[3][2]); acc[3][3] = fmaf(a3, b.w, acc[3][3]);
    }
    __syncthreads();
  }

  const int coln = tx * 4;
  const int col = n0 + coln;
  float alpha = (flags & 32) ? alpha_p[0] : 0.f;
#pragma unroll
  for (int i = 0; i < 4; i++) {
    int row = m0 + ty * 4 + i;
    if (row < M) {
      float v0 = acc[i][0], v1 = acc[i][1], v2 = acc[i][2], v3 = acc[i][3];
      size_t off = (size_t)row * ldc + col;
      if (flags & 4) {
        float4 s = *(const float4*)(Csrc + off);
        v0 += s.x; v1 += s.y; v2 += s.z; v3 += s.w;
      }
      if (flags & 1) {
        v0 += bias[col + 0]; v1 += bias[col + 1]; v2 += bias[col + 2]; v3 += bias[col + 3];
      }
      if (flags & 2) {
        v0 = fmaxf(v0, 0.f); v1 = fmaxf(v1, 0.f); v2 = fmaxf(v2, 0.f); v3 = fmaxf(v3, 0.f);
      }
      if (flags & 32) {
        v0 = (v0 >= 0.f) ? v0 : alpha * v0; v1 = (v1 >= 0.f) ? v1 : alpha * v1;
        v2 = (v2 >= 0.f) ? v2 : alpha * v2; v3 = (v3 >= 0.f) ? v3 : alpha * v3;
      }
      *(float4*)&C[off] = make_float4(v0, v1, v2, v3);
    }
  }
}

// Build WT[64][384]: cols 0..191 = gru_W_ih^T, 192..383 = gru_W_hh^T
__global__ __launch_bounds__(256) void prep_wt_k(
    const float* __restrict__ Wih, const float* __restrict__ Whh, float* __restrict__ WT)
{
  int idx = blockIdx.x * 256 + threadIdx.x;
  if (idx >= 64 * 384) return;
  int k = idx / 384, j = idx % 384;
  WT[idx] = (j < 192) ? Wih[j * 64 + k] : Whh[(j - 192) * 64 + k];
}

// Transpose LSTM weights: Tih[256,512] = lWih^T, Thh[128,512] = lWhh^T
__global__ __launch_bounds__(256) void prep_lstmT_k(
    const float* __restrict__ Wih, const float* __restrict__ Whh,
    float* __restrict__ Tih, float* __restrict__ Thh)
{
  int idx = blockIdx.x * 256 + threadIdx.x;
  if (idx < 256 * 512) {
    int j = idx / 512, r = idx % 512;
    Tih[idx] = Wih[(size_t)r * 256 + j];
  } else if (idx < 256 * 512 + 128 * 512) {
    int id2 = idx - 256 * 512;
    int j = id2 / 512, r = id2 % 512;
    Thh[id2] = Whh[(size_t)r * 128 + j];
  }
}

// One wave per edge: msg[o] = Ybias[src][o] + sum_c ea[e,c]*Y[src, c*64+o]; atomic into aggr[dst]
__global__ __launch_bounds__(256) void edge_msg_k(
    const int* __restrict__ ei, const float* __restrict__ ea,
    const float* __restrict__ Y, float* __restrict__ aggr)
{
  int gw = (blockIdx.x * blockDim.x + threadIdx.x) >> 6;
  if (gw >= NE) return;
  int lane = threadIdx.x & 63;
  int src = ei[gw];
  int dst = ei[NE + gw];
  const float* y = Y + (size_t)src * YCOLS;
  const float* eav = ea + (size_t)gw * 16;
  float4 e0 = *(const float4*)(eav + 0);
  float4 e1 = *(const float4*)(eav + 4);
  float4 e2 = *(const float4*)(eav + 8);
  float4 e3 = *(const float4*)(eav + 12);
  float msg = y[1024 + lane];
  msg = fmaf(e0.x, y[0 * 64 + lane], msg);  msg = fmaf(e0.y, y[1 * 64 + lane], msg);
  msg = fmaf(e0.z, y[2 * 64 + lane], msg);  msg = fmaf(e0.w, y[3 * 64 + lane], msg);
  msg = fmaf(e1.x, y[4 * 64 + lane], msg);  msg = fmaf(e1.y, y[5 * 64 + lane], msg);
  msg = fmaf(e1.z, y[6 * 64 + lane], msg);  msg = fmaf(e1.w, y[7 * 64 + lane], msg);
  msg = fmaf(e2.x, y[8 * 64 + lane], msg);  msg = fmaf(e2.y, y[9 * 64 + lane], msg);
  msg = fmaf(e2.z, y[10 * 64 + lane], msg); msg = fmaf(e2.w, y[11 * 64 + lane], msg);
  msg = fmaf(e3.x, y[12 * 64 + lane], msg); msg = fmaf(e3.y, y[13 * 64 + lane], msg);
  msg = fmaf(e3.z, y[14 * 64 + lane], msg); msg = fmaf(e3.w, y[15 * 64 + lane], msg);
  atomicAdd(&aggr[(size_t)dst * 64 + lane], msg);
}

// GRU elementwise: h = (1-z)*n + z*h
__global__ __launch_bounds__(256) void gru_elem_k(
    const float* __restrict__ gi, const float* __restrict__ gh, float* __restrict__ h)
{
  int t = blockIdx.x * 256 + threadIdx.x;
  if (t >= NN * 64) return;
  int n = t >> 6, c = t & 63;
  const float* gin = gi + (size_t)n * 192;
  const float* ghn = gh + (size_t)n * 192;
  float r = sigmoidf_(gin[c] + ghn[c]);
  float z = sigmoidf_(gin[64 + c] + ghn[64 + c]);
  float ng = tanhf(gin[128 + c] + r * ghn[128 + c]);
  float hv = h[t];
  h[t] = (1.f - z) * ng + z * hv;
}

// xcat = [h0, h]; p_borylation = h @ W_cls + b_cls  (one wave per node)
__global__ __launch_bounds__(256) void xcat_cls_k(
    const float* __restrict__ h0, const float* __restrict__ h,
    const float* __restrict__ Wcls, const float* __restrict__ bcls,
    float* __restrict__ xcat, float* __restrict__ out)
{
  int gw = (blockIdx.x * blockDim.x + threadIdx.x) >> 6;
  if (gw >= NN) return;
  int lane = threadIdx.x & 63;
  float hv = h[(size_t)gw * 64 + lane];
  xcat[(size_t)gw * 128 + lane] = h0[(size_t)gw * 64 + lane];
  xcat[(size_t)gw * 128 + 64 + lane] = hv;
  float p = hv * Wcls[lane];
#pragma unroll
  for (int off = 32; off > 0; off >>= 1) p += __shfl_xor(p, off);
  if (lane == 0) out[gw] = p + bcls[0];
}

// LSTM gates elementwise: gts[500,512] (+biases) -> update hs, cs
__global__ __launch_bounds__(256) void lstm_elem_k(
    const float* __restrict__ gts, const float* __restrict__ bih, const float* __restrict__ bhh,
    float* __restrict__ hs, float* __restrict__ cs)
{
  int t = blockIdx.x * 256 + threadIdx.x;
  if (t >= NB * 128) return;
  int b = t >> 7, d = t & 127;
  const float* g = gts + (size_t)b * 512;
  float iv = sigmoidf_(g[d] + bih[d] + bhh[d]);
  float fv = sigmoidf_(g[128 + d] + bih[128 + d] + bhh[128 + d]);
  float gv = tanhf(g[256 + d] + bih[256 + d] + bhh[256 + d]);
  float ov = sigmoidf_(g[384 + d] + bih[384 + d] + bhh[384 + d]);
  float c = fv * cs[t] + iv * gv;
  cs[t] = c;
  hs[t] = ov * tanhf(c);
}

// Segment-softmax attention + readout: one block per graph
__global__ __launch_bounds__(256) void attn_k(
    const float* __restrict__ xcat, const int* __restrict__ batch,
    const float* __restrict__ hs, float* __restrict__ e_ws, float* __restrict__ q_star)
{
  __shared__ float q[128];
  __shared__ float red[4];
  __shared__ float rvw[4 * 128];
  __shared__ float dw[4];
  __shared__ int se[2];
  int b = blockIdx.x;
  int tid = threadIdx.x;
  if (tid < 128) q[tid] = hs[(size_t)b * 128 + tid];
  if (tid == 254) se[0] = lower_bound_i(batch, NN, b);
  if (tid == 255) se[1] = lower_bound_i(batch, NN, b + 1);
  __syncthreads();
  int start = se[0], end = se[1];
  int lane = tid & 63, w = tid >> 6;
  float wmax = -INFINITY;
  for (int n = start + w; n < end; n += 4) {
    const float* xr = xcat + (size_t)n * 128;
    float p = xr[lane] * q[lane] + xr[64 + lane] * q[64 + lane];
#pragma unroll
    for (int off = 32; off > 0; off >>= 1) p += __shfl_xor(p, off);
    if (lane == 0) e_ws[n] = p;
    wmax = fmaxf(wmax, p);
  }
  if (lane == 0) red[w] = wmax;
  __syncthreads();
  float bmax = fmaxf(fmaxf(red[0], red[1]), fmaxf(red[2], red[3]));
  float a0 = 0.f, a1 = 0.f, ds = 0.f;
  for (int n = start + w; n < end; n += 4) {
    float ex = expf(e_ws[n] - bmax);
    const float* xr = xcat + (size_t)n * 128;
    a0 = fmaf(ex, xr[lane], a0);
    a1 = fmaf(ex, xr[64 + lane], a1);
    ds += ex;
  }
  rvw[w * 128 + lane] = a0;
  rvw[w * 128 + 64 + lane] = a1;
  if (lane == 0) dw[w] = ds;
  __syncthreads();
  if (tid < 128) {
    float r = rvw[tid] + rvw[128 + tid] + rvw[256 + tid] + rvw[384 + tid];
    float dsum = dw[0] + dw[1] + dw[2] + dw[3];
    q_star[(size_t)b * 256 + tid] = q[tid];
    q_star[(size_t)b * 256 + 128 + tid] = (end > start) ? (r / dsum) : 0.f;
  }
}

// Final scalar head: y = y1 @ Wy2 + by2 (one wave per graph)
__global__ __launch_bounds__(256) void yout_k(
    const float* __restrict__ y1, const float* __restrict__ Wy2,
    const float* __restrict__ by2, float* __restrict__ out)
{
  int gw = (blockIdx.x * blockDim.x + threadIdx.x) >> 6;
  if (gw >= NB) return;
  int lane = threadIdx.x & 63;
  const float* yr = y1 + (size_t)gw * 128;
  float p = yr[lane] * Wy2[lane] + yr[64 + lane] * Wy2[64 + lane];
#pragma unroll
  for (int off = 32; off > 0; off >>= 1) p += __shfl_xor(p, off);
  if (lane == 0) out[gw] = p + by2[0];
}

extern "C" void kernel_launch(void* const* d_in, const int* in_sizes, int n_in,
                              void* d_out, int out_size, void* d_ws, size_t ws_size,
                              hipStream_t stream) {
  const float* x      = (const float*)d_in[0];
  const int*   ei     = (const int*)d_in[1];
  const float* ea     = (const float*)d_in[2];
  const int*   batch  = (const int*)d_in[3];
  const float* W_proj = (const float*)d_in[4];
  const float* b_proj = (const float*)d_in[5];
  const float* W_edge = (const float*)d_in[6];
  const float* b_edge = (const float*)d_in[7];
  const float* root   = (const float*)d_in[8];
  const float* conv_b = (const float*)d_in[9];
  const float* gWih   = (const float*)d_in[10];
  const float* gWhh   = (const float*)d_in[11];
  const float* gbih   = (const float*)d_in[12];
  const float* gbhh   = (const float*)d_in[13];
  const float* Wcls   = (const float*)d_in[14];
  const float* bcls   = (const float*)d_in[15];
  const float* lWih   = (const float*)d_in[16];
  const float* lWhh   = (const float*)d_in[17];
  const float* lbih   = (const float*)d_in[18];
  const float* lbhh   = (const float*)d_in[19];
  const float* Wsp    = (const float*)d_in[20];
  const float* bsp    = (const float*)d_in[21];
  const float* pa     = (const float*)d_in[22];
  const float* Wy1    = (const float*)d_in[23];
  const float* by1    = (const float*)d_in[24];
  const float* Wy2    = (const float*)d_in[25];
  const float* by2    = (const float*)d_in[26];
  float* out = (float*)d_out;

  float* ws = (float*)d_ws;
  size_t o = 0;
  float* h0     = ws + o; o += (size_t)NN * 64;
  float* h      = ws + o; o += (size_t)NN * 64;
  float* Y      = ws + o; o += (size_t)NN * YCOLS;
  float* aggr   = ws + o; o += (size_t)NN * 64;
  float* mbuf   = ws + o; o += (size_t)NN * 64;
  float* gi     = ws + o; o += (size_t)NN * 192;
  float* gh     = ws + o; o += (size_t)NN * 192;
  float* xcat   = ws + o; o += (size_t)NN * 128;
  float* e_ws   = ws + o; o += (size_t)NN;
  float* WT     = ws + o; o += 64 * 384;
  float* q_star = ws + o; o += (size_t)NB * 256;
  float* hs     = ws + o; o += (size_t)NB * 128;
  float* cs     = ws + o; o += (size_t)NB * 128;
  float* Tih    = ws + o; o += 256 * 512;
  float* Thh    = ws + o; o += 128 * 512;
  float* gts    = ws + o; o += (size_t)NB * 512;
  float* gf     = ws + o; o += (size_t)NB * 1024;
  float* y1     = ws + o; o += (size_t)NB * 128;

  const int MT = (NN + 63) / 64;   // 469 node row tiles
  const int BT = (NB + 63) / 64;   // 8 graph row tiles

  prep_wt_k<<<96, 256, 0, stream>>>(gWih, gWhh, WT);
  prep_lstmT_k<<<768, 256, 0, stream>>>(lWih, lWhh, Tih, Thh);
  // h0 = relu(x @ W_proj + b_proj); h = h0
  gemm64_k<<<dim3(MT, 1), 256, 0, stream>>>(x, W_proj, 0, 64, h0, h, nullptr, b_proj,
                                            NN, 64, 0, 1 | 2 | 8);
  for (int step = 0; step < 3; step++) {
    hipMemsetAsync(aggr, 0, (size_t)NN * 64 * sizeof(float), stream);
    // Y[:, c*64+o] = h @ W_edge[c] (tiles 0..15); Y[:,1024+o] = h @ b_edge (tile 16)
    gemm64_k<<<dim3(MT, 17), 256, 0, stream>>>(h, W_edge, 4096, 64, Y, nullptr, nullptr, b_edge,
                                               NN, YCOLS, 0, 16);
    edge_msg_k<<<(NE * 64) / 256, 256, 0, stream>>>(ei, ea, Y, aggr);
    // m = relu(aggr + h @ root + conv_bias)
    gemm64_k<<<dim3(MT, 1), 256, 0, stream>>>(h, root, 0, 64, mbuf, nullptr, aggr, conv_b,
                                              NN, 64, 0, 1 | 2 | 4);
    // gi = m @ W_ih^T + b_ih ; gh = h @ W_hh^T + b_hh
    gemm64_k<<<dim3(MT, 3), 256, 0, stream>>>(mbuf, WT, 64, 384, gi, nullptr, nullptr, gbih,
                                              NN, 192, 0, 1);
    gemm64_k<<<dim3(MT, 3), 256, 0, stream>>>(h, WT + 192, 64, 384, gh, nullptr, nullptr, gbhh,
                                              NN, 192, 0, 1);
    gru_elem_k<<<(NN * 64) / 256, 256, 0, stream>>>(gi, gh, h);
  }
  xcat_cls_k<<<(NN * 64) / 256, 256, 0, stream>>>(h0, h, Wcls, bcls, xcat, out);
  hipMemsetAsync(q_star, 0, (size_t)NB * (256 + 128 + 128) * sizeof(float), stream);
  for (int t = 0; t < 3; t++) {
    // gts = q_star @ Tih ; gts += hs @ Thh  (biases added in lstm_elem_k)
    gemmK_k<<<dim3(BT, 8), 256, 0, stream>>>(q_star, 256, Tih, 512, gts, 512,
                                             nullptr, nullptr, nullptr, NB, 256, 0);
    gemmK_k<<<dim3(BT, 8), 256, 0, stream>>>(hs, 128, Thh, 512, gts, 512,
                                             gts, nullptr, nullptr, NB, 128, 4);
    lstm_elem_k<<<(NB * 128 + 255) / 256, 256, 0, stream>>>(gts, lbih, lbhh, hs, cs);
    attn_k<<<NB, 256, 0, stream>>>(xcat, batch, hs, e_ws, q_star);
  }
  // Head: gf = PReLU(q_star @ Wsp + bsp); y1 = relu(gf @ Wy1 + by1); y = y1 @ Wy2 + by2
  gemmK_k<<<dim3(BT, 16), 256, 0, stream>>>(q_star, 256, Wsp, 1024, gf, 1024,
                                            nullptr, bsp, pa, NB, 256, 1 | 32);
  gemmK_k<<<dim3(BT, 2), 256, 0, stream>>>(gf, 1024, Wy1, 128, y1, 128,
                                           nullptr, by1, nullptr, NB, 1024, 1 | 2);
  yout_k<<<(NB * 64 + 255) / 256, 256, 0, stream>>>(y1, Wy2, by2, out + NN);
}

// Round 4
// 807.794 us; speedup vs baseline: 1.8233x; 1.5876x over previous
//
#include <hip/hip_runtime.h>
#include <math.h>

#define NN 30000      // nodes
#define NNP 30080     // padded rows (multiple of 128) for MFMA A-operands
#define NE 60000      // edges
#define NB 500        // graphs
#define YROW 1344     // Ybig columns: 1024 Y | 64 Ybias | 64 h@root | 192 gh

typedef __attribute__((ext_vector_type(8))) short bf16x8;
typedef __attribute__((ext_vector_type(4))) float f32x4;

__device__ __forceinline__ float sigmoidf_(float x) { return 1.0f / (1.0f + expf(-x)); }

__device__ __forceinline__ unsigned short bf_hi(float x) {
  unsigned int u = __float_as_uint(x);
  u += 0x7FFF + ((u >> 16) & 1);          // round-to-nearest-even
  return (unsigned short)(u >> 16);
}
__device__ __forceinline__ float bf_f(unsigned short h) {
  return __uint_as_float(((unsigned int)h) << 16);
}
__device__ __forceinline__ void split_bf(float x, unsigned short& hi, unsigned short& lo) {
  hi = bf_hi(x);
  lo = bf_hi(x - bf_f(hi));
}

__device__ __forceinline__ int lower_bound_i(const int* __restrict__ a, int n, int v) {
  int lo = 0, hi = n;
  while (lo < hi) { int mid = (lo + hi) >> 1; if (a[mid] < v) lo = mid + 1; else hi = mid; }
  return lo;
}

// ---------------------------------------------------------------------------
// Split-bf16 MFMA GEMM: C[M, ldc-tile] = A[M,64] @ B[64,N]
// A given as hi/lo bf16 [NNP][64] row-major.
// B given pre-transposed k-contiguous: BT[col][64] hi/lo bf16.
// Block = 4 waves -> 128 rows x 64 cols; wave = 64 rows x 32 cols;
// wave tile = 4x2 MFMA tiles (16x16), K = 2 steps of 32, 3 split products.
// flags: 1 = bias[col] + relu; 2 = also store bf16 hi/lo (stride 64);
//        4 = also store fp32 C2 (stride 64)
// ---------------------------------------------------------------------------
__global__ __launch_bounds__(256) void gemm_mfma_k(
    const unsigned short* __restrict__ Ahi, const unsigned short* __restrict__ Alo,
    const unsigned short* __restrict__ Bhi, const unsigned short* __restrict__ Blo,
    float* __restrict__ C, int ldc,
    float* __restrict__ C2,
    unsigned short* __restrict__ Chi, unsigned short* __restrict__ Clo,
    const float* __restrict__ bias, int M, int flags)
{
  const int tid = threadIdx.x;
  const int wid = tid >> 6, lane = tid & 63;
  const int l15 = lane & 15, l4 = lane >> 4;
  const int r0 = blockIdx.x * 128 + (wid >> 1) * 64;
  const int c0 = blockIdx.y * 64 + (wid & 1) * 32;

  f32x4 acc[4][2];
#pragma unroll
  for (int rt = 0; rt < 4; rt++)
#pragma unroll
    for (int ct = 0; ct < 2; ct++) acc[rt][ct] = (f32x4){0.f, 0.f, 0.f, 0.f};

#pragma unroll
  for (int ks = 0; ks < 2; ks++) {
    const int kb = ks * 32 + l4 * 8;
    bf16x8 a_h[4], a_l[4], b_h[2], b_l[2];
#pragma unroll
    for (int rt = 0; rt < 4; rt++) {
      size_t off = (size_t)(r0 + rt * 16 + l15) * 64 + kb;
      a_h[rt] = *(const bf16x8*)(Ahi + off);
      a_l[rt] = *(const bf16x8*)(Alo + off);
    }
#pragma unroll
    for (int ct = 0; ct < 2; ct++) {
      size_t off = (size_t)(c0 + ct * 16 + l15) * 64 + kb;
      b_h[ct] = *(const bf16x8*)(Bhi + off);
      b_l[ct] = *(const bf16x8*)(Blo + off);
    }
#pragma unroll
    for (int rt = 0; rt < 4; rt++)
#pragma unroll
      for (int ct = 0; ct < 2; ct++) {
        acc[rt][ct] = __builtin_amdgcn_mfma_f32_16x16x32_bf16(a_h[rt], b_h[ct], acc[rt][ct], 0, 0, 0);
        acc[rt][ct] = __builtin_amdgcn_mfma_f32_16x16x32_bf16(a_h[rt], b_l[ct], acc[rt][ct], 0, 0, 0);
        acc[rt][ct] = __builtin_amdgcn_mfma_f32_16x16x32_bf16(a_l[rt], b_h[ct], acc[rt][ct], 0, 0, 0);
      }
  }

  // Epilogue. C/D layout (m89-verified): col = lane&15, row = (lane>>4)*4 + reg
#pragma unroll
  for (int rt = 0; rt < 4; rt++) {
    const int rbase = r0 + rt * 16 + l4 * 4;
#pragma unroll
    for (int ct = 0; ct < 2; ct++) {
      const int col = c0 + ct * 16 + l15;
      const float bv = (flags & 1) ? bias[col] : 0.f;
#pragma unroll
      for (int reg = 0; reg < 4; reg++) {
        const int row = rbase + reg;
        if (row < M) {
          float v = acc[rt][ct][reg];
          if (flags & 1) v = fmaxf(v + bv, 0.f);
          C[(size_t)row * ldc + col] = v;
          if (flags & 4) C2[(size_t)row * 64 + col] = v;
          if (flags & 2) {
            unsigned short h, l;
            split_bf(v, h, l);
            Chi[(size_t)row * 64 + col] = h;
            Clo[(size_t)row * 64 + col] = l;
          }
        }
      }
    }
  }
}

// Build all transposed split-bf16 B matrices:
//  BTbig[1344][64]: col<1024: W_edge[c, k*64+o]; <1088: b_edge[k*64+o];
//                   <1152: root[k*64+o]; else gWhh[(col-1152)*64+k]
//  BTih[192][64] = gWih[j*64+k];  BTproj[64][64] = W_proj[k*64+o]
__global__ __launch_bounds__(256) void prep_bt_k(
    const float* __restrict__ W_edge, const float* __restrict__ b_edge,
    const float* __restrict__ root, const float* __restrict__ gWhh,
    const float* __restrict__ gWih, const float* __restrict__ W_proj,
    unsigned short* __restrict__ BTbig_hi, unsigned short* __restrict__ BTbig_lo,
    unsigned short* __restrict__ BTih_hi, unsigned short* __restrict__ BTih_lo,
    unsigned short* __restrict__ BTp_hi, unsigned short* __restrict__ BTp_lo)
{
  int idx = blockIdx.x * 256 + threadIdx.x;
  const int NBIG = YROW * 64, NIH = 192 * 64, NP = 64 * 64;
  if (idx < NBIG) {
    int col = idx >> 6, k = idx & 63;
    float v;
    if (col < 1024) { int c = col >> 6, o2 = col & 63; v = W_edge[(size_t)c * 4096 + k * 64 + o2]; }
    else if (col < 1088) v = b_edge[k * 64 + (col - 1024)];
    else if (col < 1152) v = root[k * 64 + (col - 1088)];
    else v = gWhh[(size_t)(col - 1152) * 64 + k];
    unsigned short h, l; split_bf(v, h, l);
    BTbig_hi[idx] = h; BTbig_lo[idx] = l;
  } else if (idx < NBIG + NIH) {
    int i2 = idx - NBIG;
    float v = gWih[i2];  // BTih[j][k] = gWih[j*64+k] — identity layout
    unsigned short h, l; split_bf(v, h, l);
    BTih_hi[i2] = h; BTih_lo[i2] = l;
  } else if (idx < NBIG + NIH + NP) {
    int i2 = idx - NBIG - NIH;
    int o2 = i2 >> 6, k = i2 & 63;
    float v = W_proj[k * 64 + o2];
    unsigned short h, l; split_bf(v, h, l);
    BTp_hi[i2] = h; BTp_lo[i2] = l;
  }
}

// Transpose LSTM weights: Tih[256,512] = lWih^T, Thh[128,512] = lWhh^T (fp32 path)
__global__ __launch_bounds__(256) void prep_lstmT_k(
    const float* __restrict__ Wih, const float* __restrict__ Whh,
    float* __restrict__ Tih, float* __restrict__ Thh)
{
  int idx = blockIdx.x * 256 + threadIdx.x;
  if (idx < 256 * 512) {
    int j = idx / 512, r = idx % 512;
    Tih[idx] = Wih[(size_t)r * 256 + j];
  } else if (idx < 256 * 512 + 128 * 512) {
    int id2 = idx - 256 * 512;
    int j = id2 / 512, r = id2 % 512;
    Thh[id2] = Whh[(size_t)r * 128 + j];
  }
}

// x -> hi/lo bf16 (vectorized), n4 = NN*64/4
__global__ __launch_bounds__(256) void split2_k(
    const float* __restrict__ src, unsigned short* __restrict__ hi,
    unsigned short* __restrict__ lo, int n4)
{
  int i = blockIdx.x * 256 + threadIdx.x;
  if (i >= n4) return;
  float4 v = ((const float4*)src)[i];
  unsigned short h0, l0, h1, l1, h2, l2, h3, l3;
  split_bf(v.x, h0, l0); split_bf(v.y, h1, l1);
  split_bf(v.z, h2, l2); split_bf(v.w, h3, l3);
  ((ushort4*)hi)[i] = make_ushort4(h0, h1, h2, h3);
  ((ushort4*)lo)[i] = make_ushort4(l0, l1, l2, l3);
}

// One wave per edge; atomics land on the h@root slice of Ybig (cols 1088..1151)
__global__ __launch_bounds__(256) void edge_msg_k(
    const int* __restrict__ ei, const float* __restrict__ ea, float* __restrict__ Yb)
{
  int gw = (blockIdx.x * blockDim.x + threadIdx.x) >> 6;
  if (gw >= NE) return;
  int lane = threadIdx.x & 63;
  int src = ei[gw];
  int dst = ei[NE + gw];
  const float* y = Yb + (size_t)src * YROW;
  const float* eav = ea + (size_t)gw * 16;
  float4 e0 = *(const float4*)(eav + 0);
  float4 e1 = *(const float4*)(eav + 4);
  float4 e2 = *(const float4*)(eav + 8);
  float4 e3 = *(const float4*)(eav + 12);
  float msg = y[1024 + lane];
  msg = fmaf(e0.x, y[0 * 64 + lane], msg);  msg = fmaf(e0.y, y[1 * 64 + lane], msg);
  msg = fmaf(e0.z, y[2 * 64 + lane], msg);  msg = fmaf(e0.w, y[3 * 64 + lane], msg);
  msg = fmaf(e1.x, y[4 * 64 + lane], msg);  msg = fmaf(e1.y, y[5 * 64 + lane], msg);
  msg = fmaf(e1.z, y[6 * 64 + lane], msg);  msg = fmaf(e1.w, y[7 * 64 + lane], msg);
  msg = fmaf(e2.x, y[8 * 64 + lane], msg);  msg = fmaf(e2.y, y[9 * 64 + lane], msg);
  msg = fmaf(e2.z, y[10 * 64 + lane], msg); msg = fmaf(e2.w, y[11 * 64 + lane], msg);
  msg = fmaf(e3.x, y[12 * 64 + lane], msg); msg = fmaf(e3.y, y[13 * 64 + lane], msg);
  msg = fmaf(e3.z, y[14 * 64 + lane], msg); msg = fmaf(e3.w, y[15 * 64 + lane], msg);
  atomicAdd(&Yb[(size_t)dst * YROW + 1088 + lane], msg);
}

// m = relu(Ybig[:,1088+c] + conv_b) -> mb_hi/lo bf16 (fused split)
__global__ __launch_bounds__(256) void m_relu_split_k(
    const float* __restrict__ Yb, const float* __restrict__ conv_b,
    unsigned short* __restrict__ mbh, unsigned short* __restrict__ mbl)
{
  int t = blockIdx.x * 256 + threadIdx.x;
  if (t >= NN * 64) return;
  int n = t >> 6, c = t & 63;
  float v = fmaxf(Yb[(size_t)n * YROW + 1088 + c] + conv_b[c], 0.f);
  unsigned short h, l; split_bf(v, h, l);
  mbh[t] = h; mbl[t] = l;
}

// GRU elementwise: h = (1-z)*n + z*h; writes h fp32 + hi/lo bf16 (fused split)
// gi[n][192] (no bias), gh = Ybig[n][1152..1343] (no bias); biases added here.
__global__ __launch_bounds__(256) void gru_split_k(
    const float* __restrict__ gi, const float* __restrict__ Yb,
    const float* __restrict__ bih, const float* __restrict__ bhh,
    float* __restrict__ h, unsigned short* __restrict__ hh, unsigned short* __restrict__ hl)
{
  int t = blockIdx.x * 256 + threadIdx.x;
  if (t >= NN * 64) return;
  int n = t >> 6, c = t & 63;
  const float* gin = gi + (size_t)n * 192;
  const float* ghn = Yb + (size_t)n * YROW + 1152;
  float r = sigmoidf_(gin[c] + bih[c] + ghn[c] + bhh[c]);
  float z = sigmoidf_(gin[64 + c] + bih[64 + c] + ghn[64 + c] + bhh[64 + c]);
  float ng = tanhf(gin[128 + c] + bih[128 + c] + r * (ghn[128 + c] + bhh[128 + c]));
  float hv = h[t];
  float hn = (1.f - z) * ng + z * hv;
  h[t] = hn;
  unsigned short hb, lb; split_bf(hn, hb, lb);
  hh[t] = hb; hl[t] = lb;
}

// xcat[:,64:128] = h; p_borylation = h @ W_cls + b_cls  (one wave per node)
__global__ __launch_bounds__(256) void cls_xcat_k(
    const float* __restrict__ h, const float* __restrict__ Wcls,
    const float* __restrict__ bcls, float* __restrict__ xcat, float* __restrict__ out)
{
  int gw = (blockIdx.x * blockDim.x + threadIdx.x) >> 6;
  if (gw >= NN) return;
  int lane = threadIdx.x & 63;
  float hv = h[(size_t)gw * 64 + lane];
  xcat[(size_t)gw * 128 + 64 + lane] = hv;
  float p = hv * Wcls[lane];
#pragma unroll
  for (int off = 32; off > 0; off >>= 1) p += __shfl_xor(p, off);
  if (lane == 0) out[gw] = p + bcls[0];
}

// ---------------------------------------------------------------------------
// fp32 K-loop GEMM for the tiny B=500 layers (proven in round 3)
// flags: 1=bias[n], 2=relu, 4=add Csrc, 32=PReLU(alpha_p[0])
// ---------------------------------------------------------------------------
__global__ __launch_bounds__(256) void gemmK_k(
    const float* __restrict__ A, int lda,
    const float* __restrict__ B, int ldb,
    float* __restrict__ C, int ldc,
    const float* __restrict__ Csrc,
    const float* __restrict__ bias, const float* __restrict__ alpha_p,
    int M, int K, int flags)
{
  __shared__ float As[64 * 68];
  __shared__ float Bs[64 * 64];
  const int tid = threadIdx.x;
  const int m0 = blockIdx.x * 64;
  const int n0 = blockIdx.y * 64;
  const int tx = tid & 15, ty = tid >> 4;
  float acc[4][4] = {};

  for (int kc = 0; kc < K; kc += 64) {
#pragma unroll
    for (int i = 0; i < 4; i++) {
      int f4 = tid + i * 256;
      int row = f4 >> 4;
      int kk = (f4 & 15) << 2;
      float4 v = make_float4(0.f, 0.f, 0.f, 0.f);
      if (m0 + row < M) v = *(const float4*)(A + (size_t)(m0 + row) * lda + kc + kk);
      *(float4*)&As[row * 68 + kk] = v;
    }
#pragma unroll
    for (int i = 0; i < 4; i++) {
      int f4 = tid + i * 256;
      int kk = f4 >> 4;
      int nn = (f4 & 15) << 2;
      float4 v = *(const float4*)(B + (size_t)(kc + kk) * ldb + n0 + nn);
      *(float4*)&Bs[kk * 64 + nn] = v;
    }
    __syncthreads();
    const float* As0 = As + (ty * 4 + 0) * 68;
    const float* As1 = As + (ty * 4 + 1) * 68;
    const float* As2 = As + (ty * 4 + 2) * 68;
    const float* As3 = As + (ty * 4 + 3) * 68;
#pragma unroll
    for (int k = 0; k < 64; k++) {
      float4 b = *(const float4*)(Bs + k * 64 + tx * 4);
      float a0 = As0[k], a1 = As1[k], a2 = As2[k], a3 = As3[k];
      acc[0][0] = fmaf(a0, b.x, acc[0][0]); acc[0][1] = fmaf(a0, b.y, acc[0][1]);
      acc[0][2] = fmaf(a0, b.z, acc[0][2]); acc[0][3] = fmaf(a0, b.w, acc[0][3]);
      acc[1][0] = fmaf(a1, b.x, acc[1][0]); acc[1][1] = fmaf(a1, b.y, acc[1][1]);
      acc[1][2] = fmaf(a1, b.z, acc[1][2]); acc[1][3] = fmaf(a1, b.w, acc[1][3]);
      acc[2][0] = fmaf(a2, b.x, acc[2][0]); acc[2][1] = fmaf(a2, b.y, acc[2][1]);
      acc[2][2] = fmaf(a2, b.z, acc[2][2]); acc[2][3] = fmaf(a2, b.w, acc[2][3]);
      acc[3][0] = fmaf(a3, b.x, acc[3][0]); acc[3][1] = fmaf(a3, b.y, acc[3][1]);
      acc[3][2] = fmaf(a3, b.z, acc[3][2]); acc[3][3] = fmaf(a3, b.w, acc[3][3]);
    }
    __syncthreads();
  }

  const int coln = tx * 4;
  const int col = n0 + coln;
  float alpha = (flags & 32) ? alpha_p[0] : 0.f;
#pragma unroll
  for (int i = 0; i < 4; i++) {
    int row = m0 + ty * 4 + i;
    if (row < M) {
      float v0 = acc[i][0], v1 = acc[i][1], v2 = acc[i][2], v3 = acc[i][3];
      size_t off = (size_t)row * ldc + col;
      if (flags & 4) {
        float4 s = *(const float4*)(Csrc + off);
        v0 += s.x; v1 += s.y; v2 += s.z; v3 += s.w;
      }
      if (flags & 1) {
        v0 += bias[col + 0]; v1 += bias[col + 1]; v2 += bias[col + 2]; v3 += bias[col + 3];
      }
      if (flags & 2) {
        v0 = fmaxf(v0, 0.f); v1 = fmaxf(v1, 0.f); v2 = fmaxf(v2, 0.f); v3 = fmaxf(v3, 0.f);
      }
      if (flags & 32) {
        v0 = (v0 >= 0.f) ? v0 : alpha * v0; v1 = (v1 >= 0.f) ? v1 : alpha * v1;
        v2 = (v2 >= 0.f) ? v2 : alpha * v2; v3 = (v3 >= 0.f) ? v3 : alpha * v3;
      }
      *(float4*)&C[off] = make_float4(v0, v1, v2, v3);
    }
  }
}

// LSTM gates elementwise: gts[500,512] (+biases) -> update hs, cs
__global__ __launch_bounds__(256) void lstm_elem_k(
    const float* __restrict__ gts, const float* __restrict__ bih, const float* __restrict__ bhh,
    float* __restrict__ hs, float* __restrict__ cs)
{
  int t = blockIdx.x * 256 + threadIdx.x;
  if (t >= NB * 128) return;
  int b = t >> 7, d = t & 127;
  const float* g = gts + (size_t)b * 512;
  float iv = sigmoidf_(g[d] + bih[d] + bhh[d]);
  float fv = sigmoidf_(g[128 + d] + bih[128 + d] + bhh[128 + d]);
  float gv = tanhf(g[256 + d] + bih[256 + d] + bhh[256 + d]);
  float ov = sigmoidf_(g[384 + d] + bih[384 + d] + bhh[384 + d]);
  float c = fv * cs[t] + iv * gv;
  cs[t] = c;
  hs[t] = ov * tanhf(c);
}

// Segment-softmax attention + readout: one block per graph
__global__ __launch_bounds__(256) void attn_k(
    const float* __restrict__ xcat, const int* __restrict__ batch,
    const float* __restrict__ hs, float* __restrict__ e_ws, float* __restrict__ q_star)
{
  __shared__ float q[128];
  __shared__ float red[4];
  __shared__ float rvw[4 * 128];
  __shared__ float dw[4];
  __shared__ int se[2];
  int b = blockIdx.x;
  int tid = threadIdx.x;
  if (tid < 128) q[tid] = hs[(size_t)b * 128 + tid];
  if (tid == 254) se[0] = lower_bound_i(batch, NN, b);
  if (tid == 255) se[1] = lower_bound_i(batch, NN, b + 1);
  __syncthreads();
  int start = se[0], end = se[1];
  int lane = tid & 63, w = tid >> 6;
  float wmax = -INFINITY;
  for (int n = start + w; n < end; n += 4) {
    const float* xr = xcat + (size_t)n * 128;
    float p = xr[lane] * q[lane] + xr[64 + lane] * q[64 + lane];
#pragma unroll
    for (int off = 32; off > 0; off >>= 1) p += __shfl_xor(p, off);
    if (lane == 0) e_ws[n] = p;
    wmax = fmaxf(wmax, p);
  }
  if (lane == 0) red[w] = wmax;
  __syncthreads();
  float bmax = fmaxf(fmaxf(red[0], red[1]), fmaxf(red[2], red[3]));
  float a0 = 0.f, a1 = 0.f, ds = 0.f;
  for (int n = start + w; n < end; n += 4) {
    float ex = expf(e_ws[n] - bmax);
    const float* xr = xcat + (size_t)n * 128;
    a0 = fmaf(ex, xr[lane], a0);
    a1 = fmaf(ex, xr[64 + lane], a1);
    ds += ex;
  }
  rvw[w * 128 + lane] = a0;
  rvw[w * 128 + 64 + lane] = a1;
  if (lane == 0) dw[w] = ds;
  __syncthreads();
  if (tid < 128) {
    float r = rvw[tid] + rvw[128 + tid] + rvw[256 + tid] + rvw[384 + tid];
    float dsum = dw[0] + dw[1] + dw[2] + dw[3];
    q_star[(size_t)b * 256 + tid] = q[tid];
    q_star[(size_t)b * 256 + 128 + tid] = (end > start) ? (r / dsum) : 0.f;
  }
}

// Final scalar head: y = y1 @ Wy2 + by2 (one wave per graph)
__global__ __launch_bounds__(256) void yout_k(
    const float* __restrict__ y1, const float* __restrict__ Wy2,
    const float* __restrict__ by2, float* __restrict__ out)
{
  int gw = (blockIdx.x * blockDim.x + threadIdx.x) >> 6;
  if (gw >= NB) return;
  int lane = threadIdx.x & 63;
  const float* yr = y1 + (size_t)gw * 128;
  float p = yr[lane] * Wy2[lane] + yr[64 + lane] * Wy2[64 + lane];
#pragma unroll
  for (int off = 32; off > 0; off >>= 1) p += __shfl_xor(p, off);
  if (lane == 0) out[gw] = p + by2[0];
}

extern "C" void kernel_launch(void* const* d_in, const int* in_sizes, int n_in,
                              void* d_out, int out_size, void* d_ws, size_t ws_size,
                              hipStream_t stream) {
  const float* x      = (const float*)d_in[0];
  const int*   ei     = (const int*)d_in[1];
  const float* ea     = (const float*)d_in[2];
  const int*   batch  = (const int*)d_in[3];
  const float* W_proj = (const float*)d_in[4];
  const float* b_proj = (const float*)d_in[5];
  const float* W_edge = (const float*)d_in[6];
  const float* b_edge = (const float*)d_in[7];
  const float* root   = (const float*)d_in[8];
  const float* conv_b = (const float*)d_in[9];
  const float* gWih   = (const float*)d_in[10];
  const float* gWhh   = (const float*)d_in[11];
  const float* gbih   = (const float*)d_in[12];
  const float* gbhh   = (const float*)d_in[13];
  const float* Wcls   = (const float*)d_in[14];
  const float* bcls   = (const float*)d_in[15];
  const float* lWih   = (const float*)d_in[16];
  const float* lWhh   = (const float*)d_in[17];
  const float* lbih   = (const float*)d_in[18];
  const float* lbhh   = (const float*)d_in[19];
  const float* Wsp    = (const float*)d_in[20];
  const float* bsp    = (const float*)d_in[21];
  const float* pa     = (const float*)d_in[22];
  const float* Wy1    = (const float*)d_in[23];
  const float* by1    = (const float*)d_in[24];
  const float* Wy2    = (const float*)d_in[25];
  const float* by2    = (const float*)d_in[26];
  float* out = (float*)d_out;

  float* ws = (float*)d_ws;
  size_t o = 0;
  float* h      = ws + o; o += (size_t)NN * 64;
  float* Ybig   = ws + o; o += (size_t)NN * YROW;
  float* gi     = ws + o; o += (size_t)NN * 192;
  float* xcat   = ws + o; o += (size_t)NN * 128;
  float* e_ws   = ws + o; o += (size_t)NN;
  float* q_star = ws + o; o += (size_t)NB * 256;   // q_star, hs, cs contiguous (memset)
  float* hs     = ws + o; o += (size_t)NB * 128;
  float* cs     = ws + o; o += (size_t)NB * 128;
  float* Tih    = ws + o; o += 256 * 512;
  float* Thh    = ws + o; o += 128 * 512;
  float* gts    = ws + o; o += (size_t)NB * 512;
  float* gf     = ws + o; o += (size_t)NB * 1024;
  float* y1     = ws + o; o += (size_t)NB * 128;

  unsigned short* us = (unsigned short*)(ws + o);
  size_t u = 0;
  unsigned short* hh_b   = us + u; u += (size_t)NNP * 64;  // x_hi then h_hi (aliased)
  unsigned short* hl_b   = us + u; u += (size_t)NNP * 64;  // x_lo then h_lo
  unsigned short* mbh    = us + u; u += (size_t)NNP * 64;
  unsigned short* mbl    = us + u; u += (size_t)NNP * 64;
  unsigned short* BTb_hi = us + u; u += (size_t)YROW * 64;
  unsigned short* BTb_lo = us + u; u += (size_t)YROW * 64;
  unsigned short* BTi_hi = us + u; u += (size_t)192 * 64;
  unsigned short* BTi_lo = us + u; u += (size_t)192 * 64;
  unsigned short* BTp_hi = us + u; u += (size_t)64 * 64;
  unsigned short* BTp_lo = us + u; u += (size_t)64 * 64;

  const int MT = NNP / 128;  // 235 row tiles

  prep_bt_k<<<((YROW + 192 + 64) * 64 + 255) / 256, 256, 0, stream>>>(
      W_edge, b_edge, root, gWhh, gWih, W_proj,
      BTb_hi, BTb_lo, BTi_hi, BTi_lo, BTp_hi, BTp_lo);
  prep_lstmT_k<<<768, 256, 0, stream>>>(lWih, lWhh, Tih, Thh);
  split2_k<<<(NN * 16 + 255) / 256, 256, 0, stream>>>(x, hh_b, hl_b, NN * 16);

  // h0 = relu(x @ W_proj + b_proj) -> xcat[:,0:64] (fp32), h (fp32), hh/hl (bf16)
  gemm_mfma_k<<<dim3(MT, 1), 256, 0, stream>>>(hh_b, hl_b, BTp_hi, BTp_lo,
                                               xcat, 128, h, hh_b, hl_b, b_proj, NN, 1 | 2 | 4);
  for (int step = 0; step < 3; step++) {
    // Ybig = h @ [W_edge | b_edge | root | Whh^T]
    gemm_mfma_k<<<dim3(MT, YROW / 64), 256, 0, stream>>>(hh_b, hl_b, BTb_hi, BTb_lo,
                                                         Ybig, YROW, nullptr, nullptr, nullptr,
                                                         nullptr, NN, 0);
    edge_msg_k<<<(NE * 64) / 256, 256, 0, stream>>>(ei, ea, Ybig);
    m_relu_split_k<<<(NN * 64) / 256, 256, 0, stream>>>(Ybig, conv_b, mbh, mbl);
    // gi = m @ Wih^T
    gemm_mfma_k<<<dim3(MT, 3), 256, 0, stream>>>(mbh, mbl, BTi_hi, BTi_lo,
                                                 gi, 192, nullptr, nullptr, nullptr,
                                                 nullptr, NN, 0);
    gru_split_k<<<(NN * 64) / 256, 256, 0, stream>>>(gi, Ybig, gbih, gbhh, h, hh_b, hl_b);
  }
  cls_xcat_k<<<(NN * 64) / 256, 256, 0, stream>>>(h, Wcls, bcls, xcat, out);
  hipMemsetAsync(q_star, 0, (size_t)NB * (256 + 128 + 128) * sizeof(float), stream);
  for (int t = 0; t < 3; t++) {
    gemmK_k<<<dim3(8, 8), 256, 0, stream>>>(q_star, 256, Tih, 512, gts, 512,
                                            nullptr, nullptr, nullptr, NB, 256, 0);
    gemmK_k<<<dim3(8, 8), 256, 0, stream>>>(hs, 128, Thh, 512, gts, 512,
                                            gts, nullptr, nullptr, NB, 128, 4);
    lstm_elem_k<<<(NB * 128 + 255) / 256, 256, 0, stream>>>(gts, lbih, lbhh, hs, cs);
    attn_k<<<NB, 256, 0, stream>>>(xcat, batch, hs, e_ws, q_star);
  }
  gemmK_k<<<dim3(8, 16), 256, 0, stream>>>(q_star, 256, Wsp, 1024, gf, 1024,
                                           nullptr, bsp, pa, NB, 256, 1 | 32);
  gemmK_k<<<dim3(8, 2), 256, 0, stream>>>(gf, 1024, Wy1, 128, y1, 128,
                                          nullptr, by1, nullptr, NB, 1024, 1 | 2);
  yout_k<<<(NB * 64 + 255) / 256, 256, 0, stream>>>(y1, Wy2, by2, out + NN);
}

// Round 5
// 776.152 us; speedup vs baseline: 1.8976x; 1.0408x over previous
//
#include <hip/hip_runtime.h>
#include <math.h>

#define NN 30000      // nodes
#define NNP 30080     // padded rows (multiple of 128) for MFMA A-operands
#define NE 60000      // edges
#define NB 500        // graphs
#define YGH 256       // Ybig columns: 64 h@root(+msg aggr) | 192 gh
#define KE 1088       // implicit edge-GEMM K: 16*64 (ea x W_edge) + 64 (b_edge)

typedef __attribute__((ext_vector_type(8))) short bf16x8;
typedef __attribute__((ext_vector_type(4))) float f32x4;

__device__ __forceinline__ float sigmoidf_(float x) { return 1.0f / (1.0f + expf(-x)); }

__device__ __forceinline__ unsigned short bf_hi(float x) {
  unsigned int u = __float_as_uint(x);
  u += 0x7FFF + ((u >> 16) & 1);          // round-to-nearest-even
  return (unsigned short)(u >> 16);
}
__device__ __forceinline__ float bf_f(unsigned short h) {
  return __uint_as_float(((unsigned int)h) << 16);
}
__device__ __forceinline__ void split_bf(float x, unsigned short& hi, unsigned short& lo) {
  hi = bf_hi(x);
  lo = bf_hi(x - bf_f(hi));
}

__device__ __forceinline__ int lower_bound_i(const int* __restrict__ a, int n, int v) {
  int lo = 0, hi = n;
  while (lo < hi) { int mid = (lo + hi) >> 1; if (a[mid] < v) lo = mid + 1; else hi = mid; }
  return lo;
}

// ---------------------------------------------------------------------------
// Split-bf16 MFMA GEMM: C[M, ldc-tile] = A[M,64] @ B[64,N]  (round-4 verified)
// flags: 1 = bias[col] + relu; 2 = also store bf16 hi/lo (stride 64);
//        4 = also store fp32 C2 (stride 64)
// ---------------------------------------------------------------------------
__global__ __launch_bounds__(256) void gemm_mfma_k(
    const unsigned short* __restrict__ Ahi, const unsigned short* __restrict__ Alo,
    const unsigned short* __restrict__ Bhi, const unsigned short* __restrict__ Blo,
    float* __restrict__ C, int ldc,
    float* __restrict__ C2,
    unsigned short* __restrict__ Chi, unsigned short* __restrict__ Clo,
    const float* __restrict__ bias, int M, int flags)
{
  const int tid = threadIdx.x;
  const int wid = tid >> 6, lane = tid & 63;
  const int l15 = lane & 15, l4 = lane >> 4;
  const int r0 = blockIdx.x * 128 + (wid >> 1) * 64;
  const int c0 = blockIdx.y * 64 + (wid & 1) * 32;

  f32x4 acc[4][2];
#pragma unroll
  for (int rt = 0; rt < 4; rt++)
#pragma unroll
    for (int ct = 0; ct < 2; ct++) acc[rt][ct] = (f32x4){0.f, 0.f, 0.f, 0.f};

#pragma unroll
  for (int ks = 0; ks < 2; ks++) {
    const int kb = ks * 32 + l4 * 8;
    bf16x8 a_h[4], a_l[4], b_h[2], b_l[2];
#pragma unroll
    for (int rt = 0; rt < 4; rt++) {
      size_t off = (size_t)(r0 + rt * 16 + l15) * 64 + kb;
      a_h[rt] = *(const bf16x8*)(Ahi + off);
      a_l[rt] = *(const bf16x8*)(Alo + off);
    }
#pragma unroll
    for (int ct = 0; ct < 2; ct++) {
      size_t off = (size_t)(c0 + ct * 16 + l15) * 64 + kb;
      b_h[ct] = *(const bf16x8*)(Bhi + off);
      b_l[ct] = *(const bf16x8*)(Blo + off);
    }
#pragma unroll
    for (int rt = 0; rt < 4; rt++)
#pragma unroll
      for (int ct = 0; ct < 2; ct++) {
        acc[rt][ct] = __builtin_amdgcn_mfma_f32_16x16x32_bf16(a_h[rt], b_h[ct], acc[rt][ct], 0, 0, 0);
        acc[rt][ct] = __builtin_amdgcn_mfma_f32_16x16x32_bf16(a_h[rt], b_l[ct], acc[rt][ct], 0, 0, 0);
        acc[rt][ct] = __builtin_amdgcn_mfma_f32_16x16x32_bf16(a_l[rt], b_h[ct], acc[rt][ct], 0, 0, 0);
      }
  }

  // Epilogue. C/D layout (m89-verified): col = lane&15, row = (lane>>4)*4 + reg
#pragma unroll
  for (int rt = 0; rt < 4; rt++) {
    const int rbase = r0 + rt * 16 + l4 * 4;
#pragma unroll
    for (int ct = 0; ct < 2; ct++) {
      const int col = c0 + ct * 16 + l15;
      const float bv = (flags & 1) ? bias[col] : 0.f;
#pragma unroll
      for (int reg = 0; reg < 4; reg++) {
        const int row = rbase + reg;
        if (row < M) {
          float v = acc[rt][ct][reg];
          if (flags & 1) v = fmaxf(v + bv, 0.f);
          C[(size_t)row * ldc + col] = v;
          if (flags & 4) C2[(size_t)row * 64 + col] = v;
          if (flags & 2) {
            unsigned short h, l;
            split_bf(v, h, l);
            Chi[(size_t)row * 64 + col] = h;
            Clo[(size_t)row * 64 + col] = l;
          }
        }
      }
    }
  }
}

// ---------------------------------------------------------------------------
// Implicit edge GEMM: msg[e,o] = sum_{k'=c*64+kk} (ea[e,c]*h[src[e],kk]) * W2[k',o]
// (c==16 block has ea==1, folding the b_edge term). A-fragments built in
// registers (fp32 product -> split-bf16); B = W2T[64][1088] hi/lo, L2-resident.
// Wave = 64 edges x 64 outputs; block = 4 waves = 256 edges.
// Output: atomicAdd into Ybig[dst][0..63] (pre-loaded with h@root by GEMM).
// ---------------------------------------------------------------------------
__global__ __launch_bounds__(256) void edge_mfma_k(
    const int* __restrict__ ei, const float* __restrict__ ea,
    const float* __restrict__ h,
    const unsigned short* __restrict__ Whi, const unsigned short* __restrict__ Wlo,
    float* __restrict__ Yb)
{
  const int tid = threadIdx.x;
  const int wid = tid >> 6, lane = tid & 63;
  const int l15 = lane & 15, l4 = lane >> 4;
  const int e0 = (blockIdx.x * 4 + wid) * 64;

  int srcA[4];
  const float* eaA[4];
#pragma unroll
  for (int rt = 0; rt < 4; rt++) {
    int e = e0 + rt * 16 + l15;
    int ee = (e < NE) ? e : (NE - 1);
    srcA[rt] = ei[ee];
    eaA[rt] = ea + (size_t)ee * 16;
  }

  f32x4 acc[4][4];
#pragma unroll
  for (int rt = 0; rt < 4; rt++)
#pragma unroll
    for (int ct = 0; ct < 4; ct++) acc[rt][ct] = (f32x4){0.f, 0.f, 0.f, 0.f};

  for (int ks = 0; ks < KE / 32; ks++) {
    const int base = ks * 32 + l4 * 8;     // global k' for this lane's 8 elems
    const int c = base >> 6;
    const int kb = base & 63;
    bf16x8 ah[4], al[4];
#pragma unroll
    for (int rt = 0; rt < 4; rt++) {
      float eac = (c < 16) ? eaA[rt][c] : 1.0f;
      const float* hp = h + (size_t)srcA[rt] * 64 + kb;
      float4 n0 = *(const float4*)hp;
      float4 n1 = *(const float4*)(hp + 4);
      float nv[8] = {n0.x, n0.y, n0.z, n0.w, n1.x, n1.y, n1.z, n1.w};
#pragma unroll
      for (int j = 0; j < 8; j++) {
        unsigned short hb, lb;
        split_bf(eac * nv[j], hb, lb);
        ah[rt][j] = (short)hb;
        al[rt][j] = (short)lb;
      }
    }
#pragma unroll
    for (int ct = 0; ct < 4; ct++) {
      size_t wo = (size_t)(ct * 16 + l15) * KE + base;
      bf16x8 bh = *(const bf16x8*)(Whi + wo);
      bf16x8 bl = *(const bf16x8*)(Wlo + wo);
#pragma unroll
      for (int rt = 0; rt < 4; rt++) {
        acc[rt][ct] = __builtin_amdgcn_mfma_f32_16x16x32_bf16(ah[rt], bh, acc[rt][ct], 0, 0, 0);
        acc[rt][ct] = __builtin_amdgcn_mfma_f32_16x16x32_bf16(ah[rt], bl, acc[rt][ct], 0, 0, 0);
        acc[rt][ct] = __builtin_amdgcn_mfma_f32_16x16x32_bf16(al[rt], bh, acc[rt][ct], 0, 0, 0);
      }
    }
  }

  // Scatter: D row = edge (rt*16 + l4*4 + reg), col = output (ct*16 + l15)
#pragma unroll
  for (int rt = 0; rt < 4; rt++) {
    const int er = e0 + rt * 16 + l4 * 4;
#pragma unroll
    for (int reg = 0; reg < 4; reg++) {
      const int e = er + reg;
      if (e < NE) {
        const int dst = ei[NE + e];
#pragma unroll
        for (int ct = 0; ct < 4; ct++)
          atomicAdd(&Yb[(size_t)dst * YGH + ct * 16 + l15], acc[rt][ct][reg]);
      }
    }
  }
}

// Build transposed split-bf16 weights:
//  BTbig[256][64]: col<64: root[k*64+col]; else gWhh[(col-64)*64+k]
//  W2T[64][1088]:  k'=c*64+kk: c<16: W_edge[c,kk*64+o]; c==16: b_edge[kk*64+o]
//  BTih[192][64] = gWih[j*64+k];  BTproj[64][64] = W_proj[k*64+o]
__global__ __launch_bounds__(256) void prep_bt_k(
    const float* __restrict__ W_edge, const float* __restrict__ b_edge,
    const float* __restrict__ root, const float* __restrict__ gWhh,
    const float* __restrict__ gWih, const float* __restrict__ W_proj,
    unsigned short* __restrict__ BTbig_hi, unsigned short* __restrict__ BTbig_lo,
    unsigned short* __restrict__ W2_hi, unsigned short* __restrict__ W2_lo,
    unsigned short* __restrict__ BTih_hi, unsigned short* __restrict__ BTih_lo,
    unsigned short* __restrict__ BTp_hi, unsigned short* __restrict__ BTp_lo)
{
  int idx = blockIdx.x * 256 + threadIdx.x;
  const int NBIG = YGH * 64, NW2 = 64 * KE, NIH = 192 * 64, NP = 64 * 64;
  if (idx < NBIG) {
    int col = idx >> 6, k = idx & 63;
    float v = (col < 64) ? root[k * 64 + col] : gWhh[(size_t)(col - 64) * 64 + k];
    unsigned short h, l; split_bf(v, h, l);
    BTbig_hi[idx] = h; BTbig_lo[idx] = l;
  } else if (idx < NBIG + NW2) {
    int i2 = idx - NBIG;
    int o2 = i2 / KE, kq = i2 % KE;
    int c = kq >> 6, kk = kq & 63;
    float v = (c < 16) ? W_edge[(size_t)c * 4096 + kk * 64 + o2] : b_edge[kk * 64 + o2];
    unsigned short h, l; split_bf(v, h, l);
    W2_hi[i2] = h; W2_lo[i2] = l;
  } else if (idx < NBIG + NW2 + NIH) {
    int i2 = idx - NBIG - NW2;
    float v = gWih[i2];
    unsigned short h, l; split_bf(v, h, l);
    BTih_hi[i2] = h; BTih_lo[i2] = l;
  } else if (idx < NBIG + NW2 + NIH + NP) {
    int i2 = idx - NBIG - NW2 - NIH;
    int o2 = i2 >> 6, k = i2 & 63;
    float v = W_proj[k * 64 + o2];
    unsigned short h, l; split_bf(v, h, l);
    BTp_hi[i2] = h; BTp_lo[i2] = l;
  }
}

// Transpose LSTM weights: Tih[256,512] = lWih^T, Thh[128,512] = lWhh^T (fp32 path)
__global__ __launch_bounds__(256) void prep_lstmT_k(
    const float* __restrict__ Wih, const float* __restrict__ Whh,
    float* __restrict__ Tih, float* __restrict__ Thh)
{
  int idx = blockIdx.x * 256 + threadIdx.x;
  if (idx < 256 * 512) {
    int j = idx / 512, r = idx % 512;
    Tih[idx] = Wih[(size_t)r * 256 + j];
  } else if (idx < 256 * 512 + 128 * 512) {
    int id2 = idx - 256 * 512;
    int j = id2 / 512, r = id2 % 512;
    Thh[id2] = Whh[(size_t)r * 128 + j];
  }
}

// x -> hi/lo bf16 (vectorized), n4 = NN*64/4
__global__ __launch_bounds__(256) void split2_k(
    const float* __restrict__ src, unsigned short* __restrict__ hi,
    unsigned short* __restrict__ lo, int n4)
{
  int i = blockIdx.x * 256 + threadIdx.x;
  if (i >= n4) return;
  float4 v = ((const float4*)src)[i];
  unsigned short h0, l0, h1, l1, h2, l2, h3, l3;
  split_bf(v.x, h0, l0); split_bf(v.y, h1, l1);
  split_bf(v.z, h2, l2); split_bf(v.w, h3, l3);
  ((ushort4*)hi)[i] = make_ushort4(h0, h1, h2, h3);
  ((ushort4*)lo)[i] = make_ushort4(l0, l1, l2, l3);
}

// m = relu(Ybig[:,c] + conv_b) -> mb_hi/lo bf16 (fused split)
__global__ __launch_bounds__(256) void m_relu_split_k(
    const float* __restrict__ Yb, const float* __restrict__ conv_b,
    unsigned short* __restrict__ mbh, unsigned short* __restrict__ mbl)
{
  int t = blockIdx.x * 256 + threadIdx.x;
  if (t >= NN * 64) return;
  int n = t >> 6, c = t & 63;
  float v = fmaxf(Yb[(size_t)n * YGH + c] + conv_b[c], 0.f);
  unsigned short h, l; split_bf(v, h, l);
  mbh[t] = h; mbl[t] = l;
}

// GRU elementwise: h = (1-z)*n + z*h; writes h fp32 + hi/lo bf16 (fused split)
__global__ __launch_bounds__(256) void gru_split_k(
    const float* __restrict__ gi, const float* __restrict__ Yb,
    const float* __restrict__ bih, const float* __restrict__ bhh,
    float* __restrict__ h, unsigned short* __restrict__ hh, unsigned short* __restrict__ hl)
{
  int t = blockIdx.x * 256 + threadIdx.x;
  if (t >= NN * 64) return;
  int n = t >> 6, c = t & 63;
  const float* gin = gi + (size_t)n * 192;
  const float* ghn = Yb + (size_t)n * YGH + 64;
  float r = sigmoidf_(gin[c] + bih[c] + ghn[c] + bhh[c]);
  float z = sigmoidf_(gin[64 + c] + bih[64 + c] + ghn[64 + c] + bhh[64 + c]);
  float ng = tanhf(gin[128 + c] + bih[128 + c] + r * (ghn[128 + c] + bhh[128 + c]));
  float hv = h[t];
  float hn = (1.f - z) * ng + z * hv;
  h[t] = hn;
  unsigned short hb, lb; split_bf(hn, hb, lb);
  hh[t] = hb; hl[t] = lb;
}

// xcat[:,64:128] = h; p_borylation = h @ W_cls + b_cls  (one wave per node)
__global__ __launch_bounds__(256) void cls_xcat_k(
    const float* __restrict__ h, const float* __restrict__ Wcls,
    const float* __restrict__ bcls, float* __restrict__ xcat, float* __restrict__ out)
{
  int gw = (blockIdx.x * blockDim.x + threadIdx.x) >> 6;
  if (gw >= NN) return;
  int lane = threadIdx.x & 63;
  float hv = h[(size_t)gw * 64 + lane];
  xcat[(size_t)gw * 128 + 64 + lane] = hv;
  float p = hv * Wcls[lane];
#pragma unroll
  for (int off = 32; off > 0; off >>= 1) p += __shfl_xor(p, off);
  if (lane == 0) out[gw] = p + bcls[0];
}

// ---------------------------------------------------------------------------
// fp32 K-loop GEMM for the tiny B=500 layers (round-3 verified)
// flags: 1=bias[n], 2=relu, 4=add Csrc, 32=PReLU(alpha_p[0])
// ---------------------------------------------------------------------------
__global__ __launch_bounds__(256) void gemmK_k(
    const float* __restrict__ A, int lda,
    const float* __restrict__ B, int ldb,
    float* __restrict__ C, int ldc,
    const float* __restrict__ Csrc,
    const float* __restrict__ bias, const float* __restrict__ alpha_p,
    int M, int K, int flags)
{
  __shared__ float As[64 * 68];
  __shared__ float Bs[64 * 64];
  const int tid = threadIdx.x;
  const int m0 = blockIdx.x * 64;
  const int n0 = blockIdx.y * 64;
  const int tx = tid & 15, ty = tid >> 4;
  float acc[4][4] = {};

  for (int kc = 0; kc < K; kc += 64) {
#pragma unroll
    for (int i = 0; i < 4; i++) {
      int f4 = tid + i * 256;
      int row = f4 >> 4;
      int kk = (f4 & 15) << 2;
      float4 v = make_float4(0.f, 0.f, 0.f, 0.f);
      if (m0 + row < M) v = *(const float4*)(A + (size_t)(m0 + row) * lda + kc + kk);
      *(float4*)&As[row * 68 + kk] = v;
    }
#pragma unroll
    for (int i = 0; i < 4; i++) {
      int f4 = tid + i * 256;
      int kk = f4 >> 4;
      int nn = (f4 & 15) << 2;
      float4 v = *(const float4*)(B + (size_t)(kc + kk) * ldb + n0 + nn);
      *(float4*)&Bs[kk * 64 + nn] = v;
    }
    __syncthreads();
    const float* As0 = As + (ty * 4 + 0) * 68;
    const float* As1 = As + (ty * 4 + 1) * 68;
    const float* As2 = As + (ty * 4 + 2) * 68;
    const float* As3 = As + (ty * 4 + 3) * 68;
#pragma unroll
    for (int k = 0; k < 64; k++) {
      float4 b = *(const float4*)(Bs + k * 64 + tx * 4);
      float a0 = As0[k], a1 = As1[k], a2 = As2[k], a3 = As3[k];
      acc[0][0] = fmaf(a0, b.x, acc[0][0]); acc[0][1] = fmaf(a0, b.y, acc[0][1]);
      acc[0][2] = fmaf(a0, b.z, acc[0][2]); acc[0][3] = fmaf(a0, b.w, acc[0][3]);
      acc[1][0] = fmaf(a1, b.x, acc[1][0]); acc[1][1] = fmaf(a1, b.y, acc[1][1]);
      acc[1][2] = fmaf(a1, b.z, acc[1][2]); acc[1][3] = fmaf(a1, b.w, acc[1][3]);
      acc[2][0] = fmaf(a2, b.x, acc[2][0]); acc[2][1] = fmaf(a2, b.y, acc[2][1]);
      acc[2][2] = fmaf(a2, b.z, acc[2][2]); acc[2][3] = fmaf(a2, b.w, acc[2][3]);
      acc[3][0] = fmaf(a3, b.x, acc[3][0]); acc[3][1] = fmaf(a3, b.y, acc[3][1]);
      acc[3][2] = fmaf(a3, b.z, acc[3][2]); acc[3][3] = fmaf(a3, b.w, acc[3][3]);
    }
    __syncthreads();
  }

  const int coln = tx * 4;
  const int col = n0 + coln;
  float alpha = (flags & 32) ? alpha_p[0] : 0.f;
#pragma unroll
  for (int i = 0; i < 4; i++) {
    int row = m0 + ty * 4 + i;
    if (row < M) {
      float v0 = acc[i][0], v1 = acc[i][1], v2 = acc[i][2], v3 = acc[i][3];
      size_t off = (size_t)row * ldc + col;
      if (flags & 4) {
        float4 s = *(const float4*)(Csrc + off);
        v0 += s.x; v1 += s.y; v2 += s.z; v3 += s.w;
      }
      if (flags & 1) {
        v0 += bias[col + 0]; v1 += bias[col + 1]; v2 += bias[col + 2]; v3 += bias[col + 3];
      }
      if (flags & 2) {
        v0 = fmaxf(v0, 0.f); v1 = fmaxf(v1, 0.f); v2 = fmaxf(v2, 0.f); v3 = fmaxf(v3, 0.f);
      }
      if (flags & 32) {
        v0 = (v0 >= 0.f) ? v0 : alpha * v0; v1 = (v1 >= 0.f) ? v1 : alpha * v1;
        v2 = (v2 >= 0.f) ? v2 : alpha * v2; v3 = (v3 >= 0.f) ? v3 : alpha * v3;
      }
      *(float4*)&C[off] = make_float4(v0, v1, v2, v3);
    }
  }
}

// LSTM gates elementwise: gts[500,512] (+biases) -> update hs, cs
__global__ __launch_bounds__(256) void lstm_elem_k(
    const float* __restrict__ gts, const float* __restrict__ bih, const float* __restrict__ bhh,
    float* __restrict__ hs, float* __restrict__ cs)
{
  int t = blockIdx.x * 256 + threadIdx.x;
  if (t >= NB * 128) return;
  int b = t >> 7, d = t & 127;
  const float* g = gts + (size_t)b * 512;
  float iv = sigmoidf_(g[d] + bih[d] + bhh[d]);
  float fv = sigmoidf_(g[128 + d] + bih[128 + d] + bhh[128 + d]);
  float gv = tanhf(g[256 + d] + bih[256 + d] + bhh[256 + d]);
  float ov = sigmoidf_(g[384 + d] + bih[384 + d] + bhh[384 + d]);
  float c = fv * cs[t] + iv * gv;
  cs[t] = c;
  hs[t] = ov * tanhf(c);
}

// Segment-softmax attention + readout: one block per graph
__global__ __launch_bounds__(256) void attn_k(
    const float* __restrict__ xcat, const int* __restrict__ batch,
    const float* __restrict__ hs, float* __restrict__ e_ws, float* __restrict__ q_star)
{
  __shared__ float q[128];
  __shared__ float red[4];
  __shared__ float rvw[4 * 128];
  __shared__ float dw[4];
  __shared__ int se[2];
  int b = blockIdx.x;
  int tid = threadIdx.x;
  if (tid < 128) q[tid] = hs[(size_t)b * 128 + tid];
  if (tid == 254) se[0] = lower_bound_i(batch, NN, b);
  if (tid == 255) se[1] = lower_bound_i(batch, NN, b + 1);
  __syncthreads();
  int start = se[0], end = se[1];
  int lane = tid & 63, w = tid >> 6;
  float wmax = -INFINITY;
  for (int n = start + w; n < end; n += 4) {
    const float* xr = xcat + (size_t)n * 128;
    float p = xr[lane] * q[lane] + xr[64 + lane] * q[64 + lane];
#pragma unroll
    for (int off = 32; off > 0; off >>= 1) p += __shfl_xor(p, off);
    if (lane == 0) e_ws[n] = p;
    wmax = fmaxf(wmax, p);
  }
  if (lane == 0) red[w] = wmax;
  __syncthreads();
  float bmax = fmaxf(fmaxf(red[0], red[1]), fmaxf(red[2], red[3]));
  float a0 = 0.f, a1 = 0.f, ds = 0.f;
  for (int n = start + w; n < end; n += 4) {
    float ex = expf(e_ws[n] - bmax);
    const float* xr = xcat + (size_t)n * 128;
    a0 = fmaf(ex, xr[lane], a0);
    a1 = fmaf(ex, xr[64 + lane], a1);
    ds += ex;
  }
  rvw[w * 128 + lane] = a0;
  rvw[w * 128 + 64 + lane] = a1;
  if (lane == 0) dw[w] = ds;
  __syncthreads();
  if (tid < 128) {
    float r = rvw[tid] + rvw[128 + tid] + rvw[256 + tid] + rvw[384 + tid];
    float dsum = dw[0] + dw[1] + dw[2] + dw[3];
    q_star[(size_t)b * 256 + tid] = q[tid];
    q_star[(size_t)b * 256 + 128 + tid] = (end > start) ? (r / dsum) : 0.f;
  }
}

// Final scalar head: y = y1 @ Wy2 + by2 (one wave per graph)
__global__ __launch_bounds__(256) void yout_k(
    const float* __restrict__ y1, const float* __restrict__ Wy2,
    const float* __restrict__ by2, float* __restrict__ out)
{
  int gw = (blockIdx.x * blockDim.x + threadIdx.x) >> 6;
  if (gw >= NB) return;
  int lane = threadIdx.x & 63;
  const float* yr = y1 + (size_t)gw * 128;
  float p = yr[lane] * Wy2[lane] + yr[64 + lane] * Wy2[64 + lane];
#pragma unroll
  for (int off = 32; off > 0; off >>= 1) p += __shfl_xor(p, off);
  if (lane == 0) out[gw] = p + by2[0];
}

extern "C" void kernel_launch(void* const* d_in, const int* in_sizes, int n_in,
                              void* d_out, int out_size, void* d_ws, size_t ws_size,
                              hipStream_t stream) {
  const float* x      = (const float*)d_in[0];
  const int*   ei     = (const int*)d_in[1];
  const float* ea     = (const float*)d_in[2];
  const int*   batch  = (const int*)d_in[3];
  const float* W_proj = (const float*)d_in[4];
  const float* b_proj = (const float*)d_in[5];
  const float* W_edge = (const float*)d_in[6];
  const float* b_edge = (const float*)d_in[7];
  const float* root   = (const float*)d_in[8];
  const float* conv_b = (const float*)d_in[9];
  const float* gWih   = (const float*)d_in[10];
  const float* gWhh   = (const float*)d_in[11];
  const float* gbih   = (const float*)d_in[12];
  const float* gbhh   = (const float*)d_in[13];
  const float* Wcls   = (const float*)d_in[14];
  const float* bcls   = (const float*)d_in[15];
  const float* lWih   = (const float*)d_in[16];
  const float* lWhh   = (const float*)d_in[17];
  const float* lbih   = (const float*)d_in[18];
  const float* lbhh   = (const float*)d_in[19];
  const float* Wsp    = (const float*)d_in[20];
  const float* bsp    = (const float*)d_in[21];
  const float* pa     = (const float*)d_in[22];
  const float* Wy1    = (const float*)d_in[23];
  const float* by1    = (const float*)d_in[24];
  const float* Wy2    = (const float*)d_in[25];
  const float* by2    = (const float*)d_in[26];
  float* out = (float*)d_out;

  float* ws = (float*)d_ws;
  size_t o = 0;
  float* h      = ws + o; o += (size_t)NN * 64;
  float* Ybig   = ws + o; o += (size_t)NN * YGH;
  float* gi     = ws + o; o += (size_t)NN * 192;
  float* xcat   = ws + o; o += (size_t)NN * 128;
  float* e_ws   = ws + o; o += (size_t)NN;
  float* q_star = ws + o; o += (size_t)NB * 256;   // q_star, hs, cs contiguous (memset)
  float* hs     = ws + o; o += (size_t)NB * 128;
  float* cs     = ws + o; o += (size_t)NB * 128;
  float* Tih    = ws + o; o += 256 * 512;
  float* Thh    = ws + o; o += 128 * 512;
  float* gts    = ws + o; o += (size_t)NB * 512;
  float* gf     = ws + o; o += (size_t)NB * 1024;
  float* y1     = ws + o; o += (size_t)NB * 128;

  unsigned short* us = (unsigned short*)(ws + o);
  size_t u = 0;
  unsigned short* hh_b   = us + u; u += (size_t)NNP * 64;  // x_hi then h_hi (aliased)
  unsigned short* hl_b   = us + u; u += (size_t)NNP * 64;  // x_lo then h_lo
  unsigned short* mbh    = us + u; u += (size_t)NNP * 64;
  unsigned short* mbl    = us + u; u += (size_t)NNP * 64;
  unsigned short* BTb_hi = us + u; u += (size_t)YGH * 64;
  unsigned short* BTb_lo = us + u; u += (size_t)YGH * 64;
  unsigned short* W2_hi  = us + u; u += (size_t)64 * KE;
  unsigned short* W2_lo  = us + u; u += (size_t)64 * KE;
  unsigned short* BTi_hi = us + u; u += (size_t)192 * 64;
  unsigned short* BTi_lo = us + u; u += (size_t)192 * 64;
  unsigned short* BTp_hi = us + u; u += (size_t)64 * 64;
  unsigned short* BTp_lo = us + u; u += (size_t)64 * 64;

  const int MT = NNP / 128;            // 235 node row tiles
  const int ET = (NE + 255) / 256;     // 235 edge blocks (4 waves x 64 edges)
  const int PREP_N = YGH * 64 + 64 * KE + 192 * 64 + 64 * 64;

  prep_bt_k<<<(PREP_N + 255) / 256, 256, 0, stream>>>(
      W_edge, b_edge, root, gWhh, gWih, W_proj,
      BTb_hi, BTb_lo, W2_hi, W2_lo, BTi_hi, BTi_lo, BTp_hi, BTp_lo);
  prep_lstmT_k<<<768, 256, 0, stream>>>(lWih, lWhh, Tih, Thh);
  split2_k<<<(NN * 16 + 255) / 256, 256, 0, stream>>>(x, hh_b, hl_b, NN * 16);

  // h0 = relu(x @ W_proj + b_proj) -> xcat[:,0:64] (fp32), h (fp32), hh/hl (bf16)
  gemm_mfma_k<<<dim3(MT, 1), 256, 0, stream>>>(hh_b, hl_b, BTp_hi, BTp_lo,
                                               xcat, 128, h, hh_b, hl_b, b_proj, NN, 1 | 2 | 4);
  for (int step = 0; step < 3; step++) {
    // Ybig = h @ [root | Whh^T]  (cols 0..63 seed the msg aggregation)
    gemm_mfma_k<<<dim3(MT, YGH / 64), 256, 0, stream>>>(hh_b, hl_b, BTb_hi, BTb_lo,
                                                        Ybig, YGH, nullptr, nullptr, nullptr,
                                                        nullptr, NN, 0);
    edge_mfma_k<<<ET, 256, 0, stream>>>(ei, ea, h, W2_hi, W2_lo, Ybig);
    m_relu_split_k<<<(NN * 64) / 256, 256, 0, stream>>>(Ybig, conv_b, mbh, mbl);
    // gi = m @ Wih^T
    gemm_mfma_k<<<dim3(MT, 3), 256, 0, stream>>>(mbh, mbl, BTi_hi, BTi_lo,
                                                 gi, 192, nullptr, nullptr, nullptr,
                                                 nullptr, NN, 0);
    gru_split_k<<<(NN * 64) / 256, 256, 0, stream>>>(gi, Ybig, gbih, gbhh, h, hh_b, hl_b);
  }
  cls_xcat_k<<<(NN * 64) / 256, 256, 0, stream>>>(h, Wcls, bcls, xcat, out);
  hipMemsetAsync(q_star, 0, (size_t)NB * (256 + 128 + 128) * sizeof(float), stream);
  for (int t = 0; t < 3; t++) {
    gemmK_k<<<dim3(8, 8), 256, 0, stream>>>(q_star, 256, Tih, 512, gts, 512,
                                            nullptr, nullptr, nullptr, NB, 256, 0);
    gemmK_k<<<dim3(8, 8), 256, 0, stream>>>(hs, 128, Thh, 512, gts, 512,
                                            gts, nullptr, nullptr, NB, 128, 4);
    lstm_elem_k<<<(NB * 128 + 255) / 256, 256, 0, stream>>>(gts, lbih, lbhh, hs, cs);
    attn_k<<<NB, 256, 0, stream>>>(xcat, batch, hs, e_ws, q_star);
  }
  gemmK_k<<<dim3(8, 16), 256, 0, stream>>>(q_star, 256, Wsp, 1024, gf, 1024,
                                           nullptr, bsp, pa, NB, 256, 1 | 32);
  gemmK_k<<<dim3(8, 2), 256, 0, stream>>>(gf, 1024, Wy1, 128, y1, 128,
                                          nullptr, by1, nullptr, NB, 1024, 1 | 2);
  yout_k<<<(NB * 64 + 255) / 256, 256, 0, stream>>>(y1, Wy2, by2, out + NN);
}